// Round 11
// baseline (307.664 us; speedup 1.0000x reference)
//
#include <hip/hip_runtime.h>

// Softmax splatting (softsplat 'soft', metric==1) via destination-binned GATHER.
// Round 11: LDS-STAGED gather — each block's contributors are two contiguous
// slot ranges; stage them into LDS with flat coalesced uint4 copies (chunked),
// then run the statically-unrolled per-cell walk entirely from LDS (no global
// latency in the walk). bf16 packed entries, atomicSub slot claim, bf16 pack tile.
// B=8, C=128, H=256, W=256, f32. out = [warped (B,C,H,W) | metric (B,1,H,W)=1]

typedef unsigned int u32;

static constexpr int B = 8, C = 128, H = 256, W = 256;
static constexpr int HW = H * W;
static constexpr int PH = H + 1, PW = W + 1;         // padded floor-cell grid
static constexpr int NC = B * PH * PW;               // 528392 cells
static constexpr int S  = B * HW;                    // 524288 sources
static constexpr float E1  = 2.7182818284590452354f; // exp(1) (metric == 1)
static constexpr float EPS = 1e-7f;
static constexpr int CHUNK = 1024;
static constexpr int NBLK  = (NC + CHUNK - 1) / CHUNK;  // 517
static constexpr int NCAP  = 64;                     // staged entries per row-chunk

__device__ __forceinline__ u32 bf16rne(float f) {
    const u32 u = __float_as_uint(f);
    return (u + 0x7fffu + ((u >> 16) & 1u)) >> 16;
}

// ---------------- binning ----------------

__global__ __launch_bounds__(256) void count_kernel(const float* __restrict__ flow,
                                                    u32* __restrict__ counts)
{
    const int x = threadIdx.x, by = blockIdx.x, b = by >> 8, y = by & 255;
    const float fx = (float)x + flow[(b * 2) * HW + y * W + x];
    const float fy = (float)y + flow[(b * 2 + 1) * HW + y * W + x];
    const int ix0 = (int)floorf(fx), iy0 = (int)floorf(fy);
    if (ix0 >= -1 && ix0 < W && iy0 >= -1 && iy0 < H)
        atomicAdd(&counts[(b * PH + iy0 + 1) * PW + (ix0 + 1)], 1u);
}

__global__ __launch_bounds__(256) void scan_blocks(const u32* __restrict__ in,
                                                   u32* __restrict__ out,
                                                   u32* __restrict__ bsum)
{
    __shared__ u32 sd[256];
    const int tid = threadIdx.x;
    const int base = blockIdx.x * CHUNK + tid * 4;
    u32 v0 = 0, v1 = 0, v2 = 0, v3 = 0;
    if (base + 3 < NC) {
        const uint4 q = *(const uint4*)(in + base);
        v0 = q.x; v1 = q.y; v2 = q.z; v3 = q.w;
    } else {
        if (base     < NC) v0 = in[base];
        if (base + 1 < NC) v1 = in[base + 1];
        if (base + 2 < NC) v2 = in[base + 2];
    }
    const u32 t = v0 + v1 + v2 + v3;
    sd[tid] = t; __syncthreads();
    for (int o = 1; o < 256; o <<= 1) {
        const u32 a = (tid >= o) ? sd[tid - o] : 0u;
        __syncthreads();
        sd[tid] += a;
        __syncthreads();
    }
    const u32 excl = sd[tid] - t;
    if (base + 3 < NC) {
        uint4 q; q.x = excl; q.y = excl + v0; q.z = excl + v0 + v1; q.w = excl + v0 + v1 + v2;
        *(uint4*)(out + base) = q;
    } else {
        if (base     < NC) out[base]     = excl;
        if (base + 1 < NC) out[base + 1] = excl + v0;
        if (base + 2 < NC) out[base + 2] = excl + v0 + v1;
    }
    if (tid == 255) bsum[blockIdx.x] = sd[255];
}

__global__ __launch_bounds__(1024) void scan_bsum(u32* __restrict__ bsum,
                                                  u32* __restrict__ off)
{
    __shared__ u32 sd[1024];
    const int tid = threadIdx.x;
    const u32 v = (tid < NBLK) ? bsum[tid] : 0u;
    sd[tid] = v; __syncthreads();
    for (int o = 1; o < 1024; o <<= 1) {
        const u32 a = (tid >= o) ? sd[tid - o] : 0u;
        __syncthreads();
        sd[tid] += a;
        __syncthreads();
    }
    if (tid < NBLK) bsum[tid] = sd[tid] - v;
    if (tid == 1023) off[NC] = sd[1023];
}

__global__ __launch_bounds__(256) void scan_add(u32* __restrict__ off,
                                                const u32* __restrict__ bsum)
{
    const u32 add = bsum[blockIdx.x];
    if (add == 0) return;
    const int base = blockIdx.x * CHUNK + threadIdx.x * 4;
    if (base + 3 < NC) {
        uint4 q = *(uint4*)(off + base);
        q.x += add; q.y += add; q.z += add; q.w += add;
        *(uint4*)(off + base) = q;
    } else {
        for (int k = 0; k < 4; ++k)
            if (base + k < NC) off[base + k] += add;
    }
}

// fill claims slots by DECREMENTING counts (no cursor memset needed)
__global__ __launch_bounds__(256) void fill_kernel(const float* __restrict__ flow,
                                                   const u32* __restrict__ off,
                                                   u32* __restrict__ cnt,
                                                   u32* __restrict__ slot_of_src,
                                                   u32* __restrict__ lpos,
                                                   float2* __restrict__ lxy)
{
    const int x = threadIdx.x, by = blockIdx.x, b = by >> 8, y = by & 255;
    const float fx = (float)x + flow[(b * 2) * HW + y * W + x];
    const float fy = (float)y + flow[(b * 2 + 1) * HW + y * W + x];
    const int ix0 = (int)floorf(fx), iy0 = (int)floorf(fy);
    const int src = b * HW + y * W + x;
    if (ix0 >= -1 && ix0 < W && iy0 >= -1 && iy0 < H) {
        const int cell = (b * PH + iy0 + 1) * PW + (ix0 + 1);
        const u32 old = atomicSub(&cnt[cell], 1u);
        const u32 slot = off[cell] + old - 1u;
        slot_of_src[src] = slot;
        lpos[slot] = (u32)(y * W + x);
        lxy[slot]  = make_float2(fx, fy);
    } else {
        slot_of_src[src] = 0xFFFFFFFFu;
    }
}

// ---------------- pack (bf16): u16 LDS tile, (c, c+64) pair -> one u32 ----------------

__global__ __launch_bounds__(256) void pack128_bf16(const float* __restrict__ feat,
                                                    const u32* __restrict__ slot_of_src,
                                                    u32* __restrict__ packed)
{
    __shared__ unsigned short lds[64 * 129];   // 16.5 KB: [pix][ch] bf16
    const int x0 = blockIdx.x * 64, y = blockIdx.y, b = blockIdx.z;
    const int tid = threadIdx.x;
    const float* fbase = feat + (size_t)(b * C) * HW + y * W + x0;
    for (int idx = tid; idx < 128 * 16; idx += 256) {
        const int cc = idx >> 4, i4 = (idx & 15) * 4;
        const float4 v = *(const float4*)(fbase + (size_t)cc * HW + i4);
        lds[(i4 + 0) * 129 + cc] = (unsigned short)bf16rne(v.x);
        lds[(i4 + 1) * 129 + cc] = (unsigned short)bf16rne(v.y);
        lds[(i4 + 2) * 129 + cc] = (unsigned short)bf16rne(v.z);
        lds[(i4 + 3) * 129 + cc] = (unsigned short)bf16rne(v.w);
    }
    __syncthreads();
    const int wave = tid >> 6, lane = tid & 63;
    const u32* sp = slot_of_src + (size_t)b * HW + y * W + x0;
    for (int p = wave * 16; p < wave * 16 + 16; ++p) {
        const u32 s = sp[p];
        if (s == 0xFFFFFFFFu) continue;
        const u32 lo = (u32)lds[p * 129 + lane];
        const u32 hi = (u32)lds[p * 129 + 64 + lane];
        packed[(size_t)s * 64 + lane] = lo | (hi << 16);
    }
}

// generic f32 pack (fallback path, CC<128, linear layout)
__global__ __launch_bounds__(256) void pack_kernel(const float* __restrict__ feat,
                                                   const u32* __restrict__ slot_of_src,
                                                   float* __restrict__ packed,
                                                   int c0, int CC)
{
    __shared__ float lds[64 * 129];
    const int x0 = blockIdx.x * 64, y = blockIdx.y, b = blockIdx.z;
    const int tid = threadIdx.x;
    const float* fbase = feat + (size_t)(b * C + c0) * HW + y * W + x0;
    const int n = CC * 64;
    for (int idx = tid; idx < n; idx += 256) {
        const int cc = idx >> 6, i = idx & 63;
        lds[i * 129 + cc] = fbase[(size_t)cc * HW + i];
    }
    __syncthreads();
    const int wave = tid >> 6, lane = tid & 63;
    const u32* sp = slot_of_src + (size_t)b * HW + y * W + x0;
    for (int p = wave * 16; p < wave * 16 + 16; ++p) {
        const u32 s = sp[p];
        if (s == 0xFFFFFFFFu) continue;
        float* dst = packed + (size_t)s * CC;
        for (int j = lane; j < CC; j += 64)
            dst[j] = lds[p * 129 + j];
    }
}

// ---------------- LDS-staged gather ----------------
// Block = 32 output px of one row (4 waves x 8 px). Contributors = two
// contiguous slot ranges (33 cells x 2 cell-rows). Stage each range into LDS
// (chunks of NCAP entries, flat uint4 copies), then per-wave statically
// unrolled per-cell walk reads entries from LDS only. Cell ranges are clamped
// to the chunk window, so cells split across chunks accumulate correctly.

#define KM1(K) ((K) >= 1 ? (K) - 1 : 0)
#define KK(K)  ((K) <= 7 ? (K) : 0)

#define ACCUM(K, w0, w1, dx_, dy_)                                             \
    if ((K) >= 1) {                                                            \
        acc0[KM1(K)] = fmaf(w0, dx_, acc0[KM1(K)]);                            \
        acc1[KM1(K)] = fmaf(w0, dy_, acc1[KM1(K)]);                            \
        den [KM1(K)] += w0;                                                    \
    }                                                                          \
    if ((K) <= 7) {                                                            \
        acc0[KK(K)] = fmaf(w1, dx_, acc0[KK(K)]);                              \
        acc1[KK(K)] = fmaf(w1, dy_, acc1[KK(K)]);                              \
        den [KK(K)] += w1;                                                     \
    }

#define PROC(K, xy, du)                                                        \
    {                                                                          \
        const float fr = (xy).x - (float)(oxw - 1 + (K));                      \
        const float wy = 1.f - fabsf((xy).y - foy);                            \
        const float w0 = (1.f - fr) * wy, w1 = fr * wy;                        \
        const float dx_ = __uint_as_float((du) << 16);                         \
        const float dy_ = __uint_as_float((du) & 0xffff0000u);                 \
        ACCUM(K, w0, w1, dx_, dy_)                                             \
    }

// clamped per-cell run from LDS chunk [cs, cs+n)
#define RUNC(K, bnd, cs, n, basedu, basexy)                                    \
    {                                                                          \
        const u32 i0 = bnd[K] > (cs) ? bnd[K] : (cs);                          \
        const u32 ce = (cs) + (n);                                             \
        const u32 i1 = bnd[(K) + 1] < ce ? bnd[(K) + 1] : ce;                  \
        for (u32 i = i0; i < i1; ++i) {                                        \
            const u32 li = i - (cs);                                           \
            const float2 xy = (basexy)[li];                                    \
            const u32 du = (basedu)[li * 64 + lane];                           \
            PROC(K, xy, du)                                                    \
        }                                                                      \
    }

#define ROW_ALL(bnd, cs, n, basedu, basexy)                                    \
    RUNC(0, bnd, cs, n, basedu, basexy) RUNC(1, bnd, cs, n, basedu, basexy)    \
    RUNC(2, bnd, cs, n, basedu, basexy) RUNC(3, bnd, cs, n, basedu, basexy)    \
    RUNC(4, bnd, cs, n, basedu, basexy) RUNC(5, bnd, cs, n, basedu, basexy)    \
    RUNC(6, bnd, cs, n, basedu, basexy) RUNC(7, bnd, cs, n, basedu, basexy)    \
    RUNC(8, bnd, cs, n, basedu, basexy)

__global__ __launch_bounds__(256) void gather_cells(
    const u32* __restrict__ pk, const u32* __restrict__ off,
    const float2* __restrict__ lxy, float* __restrict__ out)
{
    __shared__ u32 smem[2 * 64 * NCAP];   // 32 KB staging; reused as transpose tile
    __shared__ float2 sxyA[NCAP], sxyB[NCAP];
    __shared__ float ldsden[32];
    const int tid = threadIdx.x, wv = tid >> 6, lane = tid & 63;
    // XCD-bijective swizzle: 16384 blocks = 8 XCDs x 2048; each XCD owns one
    // batch (8 xseg x 256 rows), rows fastest -> cell-row reuse in that XCD's L2.
    const u32 bid = blockIdx.x;
    const u32 swz = (bid & 7u) * 2048u + (bid >> 3);
    const int b    = (int)(swz >> 11);
    const int xseg = (int)((swz >> 8) & 7u);
    const int row  = (int)(swz & 255u);
    const int ox0  = xseg * 32;            // block's first output x (32 px/block)
    const int oxw  = ox0 + wv * 8;         // this wave's first output x (8 px/wave)
    const float foy = (float)row;

    float acc0[8], acc1[8], den[8];
    #pragma unroll
    for (int k = 0; k < 8; ++k) { acc0[k] = 0.f; acc1[k] = 0.f; den[k] = 0.f; }

    // block-uniform range bounds + wave-uniform cell boundaries (scalar loads)
    const u32 rb0 = (u32)__builtin_amdgcn_readfirstlane(
        (int)((u32)((b * PH + row) * PW + ox0)));
    const u32 sA0 = off[rb0],      eA = off[rb0 + 33];
    const u32 sB0 = off[rb0 + PW], eB = off[rb0 + PW + 33];
    const u32 rbu = rb0 + (u32)(wv * 8);
    u32 bndA[10], bndB[10];
    #pragma unroll
    for (int q = 0; q < 10; ++q) {
        bndA[q] = off[rbu + q];        // cell-row above (padded row = row)
        bndB[q] = off[rbu + PW + q];   // cell-row at    (padded row = row+1)
    }

    u32* const duA = smem;
    u32* const duB = smem + 64 * NCAP;

    u32 csA = sA0, csB = sB0;
    while (csA < eA || csB < eB) {
        const u32 nA = (eA - csA) < (u32)NCAP ? (eA - csA) : (u32)NCAP;
        const u32 nB = (eB - csB) < (u32)NCAP ? (eB - csB) : (u32)NCAP;
        // stage: flat coalesced uint4 copies of both ranges + their lxy
        {
            const uint4* srcA = (const uint4*)(pk + (size_t)csA * 64);
            const int m4A = (int)nA * 16;
            for (int j = tid; j < m4A; j += 256) ((uint4*)duA)[j] = srcA[j];
            const uint4* srcB = (const uint4*)(pk + (size_t)csB * 64);
            const int m4B = (int)nB * 16;
            for (int j = tid; j < m4B; j += 256) ((uint4*)duB)[j] = srcB[j];
            for (int j = tid; j < (int)nA; j += 256) sxyA[j] = lxy[csA + j];
            for (int j = tid; j < (int)nB; j += 256) sxyB[j] = lxy[csB + j];
        }
        __syncthreads();
        // compute from LDS (clamped per-cell runs, static acc indices)
        ROW_ALL(bndA, csA, nA, duA, sxyA)
        ROW_ALL(bndB, csB, nB, duB, sxyB)
        csA += nA; csB += nB;
        __syncthreads();   // all reads done before next stage / tile reuse
    }

    // ---- epilogue: transpose via reused smem, normalize, coalesced writes ----
    float* const tile = (float*)smem;   // 32*65 floats = 8.3 KB
    #pragma unroll
    for (int k = 0; k < 8; ++k) {
        const int p = wv * 8 + k;
        tile[p * 65 + lane] = acc0[k];
        if (lane == 0) ldsden[p] = den[k];
    }
    __syncthreads();
    {
        const int px = tid & 31, cslot = tid >> 5;
        const float dn = ldsden[px];
        const float s  = E1 / (E1 * dn + EPS);
        #pragma unroll
        for (int j = 0; j < 8; ++j) {
            const int c = cslot * 8 + j;
            out[(size_t)(b * C + c) * HW + (size_t)row * W + ox0 + px] =
                tile[px * 65 + c] * s;
        }
    }
    __syncthreads();
    #pragma unroll
    for (int k = 0; k < 8; ++k) {
        const int p = wv * 8 + k;
        tile[p * 65 + lane] = acc1[k];
    }
    __syncthreads();
    {
        const int px = tid & 31, cslot = tid >> 5;
        const float dn = ldsden[px];
        const float s  = E1 / (E1 * dn + EPS);
        #pragma unroll
        for (int j = 0; j < 8; ++j) {
            const int c = cslot * 8 + j;
            out[(size_t)(b * C + 64 + c) * HW + (size_t)row * W + ox0 + px] =
                tile[px * 65 + c] * s;
        }
    }
    if (tid < 32)
        out[(size_t)(B * C) * HW + (size_t)b * HW + (size_t)row * W + ox0 + tid] = 1.0f;
}

// ---------------- fallback: per-thread gather from f32 packed (CC<128) ----------------

__global__ __launch_bounds__(256) void gather_packed(
    const float* __restrict__ packed, const u32* __restrict__ off,
    const float2* __restrict__ lxy, float* __restrict__ out, int c0, int CC)
{
    const int t = threadIdx.x;
    const int tile = blockIdx.x, b = blockIdx.y;
    const int ox = ((tile & 15) << 4) | (t & 15);
    const int oy = ((tile >> 4) << 4) | (t >> 4);
    const int opix = oy * W + ox;
    const u32 rb0 = (u32)((b * PH + oy) * PW + ox);
    const u32 s0 = off[rb0],      e0 = off[rb0 + 2];
    const u32 s1 = off[rb0 + PW], e1 = off[rb0 + PW + 2];
    const float fox = (float)ox, foy = (float)oy;
    float scale = 0.f;
    for (int ch = 0; ch < CC; ch += 16) {
        float acc[16];
        #pragma unroll
        for (int c = 0; c < 16; ++c) acc[c] = 0.f;
        float den = 0.f;
        for (int rr = 0; rr < 2; ++rr) {
            u32 i = rr ? s1 : s0;
            const u32 e = rr ? e1 : e0;
            for (; i < e; ++i) {
                const float2 xy = lxy[i];
                const float w = (1.f - fabsf(xy.x - fox)) * (1.f - fabsf(xy.y - foy));
                den += w;
                const float4* ep = (const float4*)(packed + (size_t)i * CC + ch);
                const float4 q0 = ep[0], q1 = ep[1], q2 = ep[2], q3 = ep[3];
                acc[ 0] = fmaf(w, q0.x, acc[ 0]); acc[ 1] = fmaf(w, q0.y, acc[ 1]);
                acc[ 2] = fmaf(w, q0.z, acc[ 2]); acc[ 3] = fmaf(w, q0.w, acc[ 3]);
                acc[ 4] = fmaf(w, q1.x, acc[ 4]); acc[ 5] = fmaf(w, q1.y, acc[ 5]);
                acc[ 6] = fmaf(w, q1.z, acc[ 6]); acc[ 7] = fmaf(w, q1.w, acc[ 7]);
                acc[ 8] = fmaf(w, q2.x, acc[ 8]); acc[ 9] = fmaf(w, q2.y, acc[ 9]);
                acc[10] = fmaf(w, q2.z, acc[10]); acc[11] = fmaf(w, q2.w, acc[11]);
                acc[12] = fmaf(w, q3.x, acc[12]); acc[13] = fmaf(w, q3.y, acc[13]);
                acc[14] = fmaf(w, q3.z, acc[14]); acc[15] = fmaf(w, q3.w, acc[15]);
            }
        }
        if (ch == 0) scale = E1 / (E1 * den + EPS);
        float* op = out + (size_t)(b * C + c0 + ch) * HW + opix;
        #pragma unroll
        for (int c = 0; c < 16; ++c) op[(size_t)c * HW] = acc[c] * scale;
    }
    if (c0 == 0)
        out[(size_t)(B * C) * HW + (size_t)b * HW + opix] = 1.0f;
}

// ---------------- fallback: planar gather ----------------

__global__ __launch_bounds__(256) void gather_kernel(
    const float* __restrict__ feat, const u32* __restrict__ off,
    const u32* __restrict__ lpos, const float2* __restrict__ lxy,
    float* __restrict__ out)
{
    const int t = threadIdx.x;
    const int tile = blockIdx.x, b = blockIdx.y;
    const int ox = ((tile & 15) << 4) | (t & 15);
    const int oy = ((tile >> 4) << 4) | (t >> 4);
    const int opix = oy * W + ox;
    const u32 rb0 = (u32)((b * PH + oy) * PW + ox);
    const u32 s0 = off[rb0],      e0 = off[rb0 + 2];
    const u32 s1 = off[rb0 + PW], e1 = off[rb0 + PW + 2];
    const float fox = (float)ox, foy = (float)oy;
    float den = 0.f;
    for (int rr = 0; rr < 2; ++rr) {
        u32 i = rr ? s1 : s0;
        const u32 e = rr ? e1 : e0;
        for (; i < e; ++i) {
            const float2 xy = lxy[i];
            den += (1.f - fabsf(xy.x - fox)) * (1.f - fabsf(xy.y - foy));
        }
    }
    const float scale = E1 / (E1 * den + EPS);
    for (int ch = 0; ch < C; ch += 16) {
        float acc[16];
        #pragma unroll
        for (int c = 0; c < 16; ++c) acc[c] = 0.f;
        const float* fb = feat + (size_t)(b * C + ch) * HW;
        for (int rr = 0; rr < 2; ++rr) {
            u32 i = rr ? s1 : s0;
            const u32 e = rr ? e1 : e0;
            for (; i < e; ++i) {
                const float2 xy = lxy[i];
                const float w = (1.f - fabsf(xy.x - fox)) * (1.f - fabsf(xy.y - foy));
                const float* fp = fb + lpos[i];
                #pragma unroll
                for (int c = 0; c < 16; ++c)
                    acc[c] = fmaf(w, fp[(size_t)c * HW], acc[c]);
            }
        }
        float* op = out + (size_t)(b * C + ch) * HW + opix;
        #pragma unroll
        for (int c = 0; c < 16; ++c) op[(size_t)c * HW] = acc[c] * scale;
    }
    out[(size_t)(B * C) * HW + (size_t)b * HW + opix] = 1.0f;
}

// ---------------- fallback: round-1 atomic path ----------------

static constexpr int CG = 8, CPG = C / CG;

__global__ __launch_bounds__(256) void splat_kernel(
    const float* __restrict__ feat, const float* __restrict__ flow,
    float* __restrict__ num, float* __restrict__ den)
{
    const int x = threadIdx.x, by = blockIdx.x, b = by >> 8, y = by & (H - 1);
    const int cg = blockIdx.y;
    const float fx = (float)x + flow[(b * 2 * H + y) * W + x];
    const float fy = (float)y + flow[((b * 2 + 1) * H + y) * W + x];
    const float x0f = floorf(fx), y0f = floorf(fy);
    const int ix0 = (int)x0f, iy0 = (int)y0f;
    const float ax = fx - x0f, ay = fy - y0f;
    const float w00 = (1.f - ax) * (1.f - ay), w10 = ax * (1.f - ay);
    const float w01 = (1.f - ax) * ay,         w11 = ax * ay;
    const bool vx0 = (unsigned)ix0       < (unsigned)W;
    const bool vx1 = (unsigned)(ix0 + 1) < (unsigned)W;
    const bool vy0 = (unsigned)iy0       < (unsigned)H;
    const bool vy1 = (unsigned)(iy0 + 1) < (unsigned)H;
    const bool v00 = vx0 && vy0, v10 = vx1 && vy0;
    const bool v01 = vx0 && vy1, v11 = vx1 && vy1;
    const int t00 = iy0 * W + ix0, t01 = t00 + W;
    if (cg == 0) {
        float* dn = den + b * HW;
        if (v00) atomicAdd(dn + t00,     w00);
        if (v10) atomicAdd(dn + t00 + 1, w10);
        if (v01) atomicAdd(dn + t01,     w01);
        if (v11) atomicAdd(dn + t01 + 1, w11);
    }
    const int c0 = cg * CPG;
    const float* fp = feat + ((size_t)(b * C + c0)) * HW + y * W + x;
    float*       np = num  + ((size_t)(b * C + c0)) * HW;
    for (int c = 0; c < CPG; ++c) {
        const float v = fp[(size_t)c * HW];
        float* nc = np + (size_t)c * HW;
        if (v00) atomicAdd(nc + t00,     v * w00);
        if (v10) atomicAdd(nc + t00 + 1, v * w10);
        if (v01) atomicAdd(nc + t01,     v * w01);
        if (v11) atomicAdd(nc + t01 + 1, v * w11);
    }
}

__global__ __launch_bounds__(256) void normalize_kernel(float* __restrict__ num,
                                                        float* __restrict__ den)
{
    const int x = threadIdx.x, by = blockIdx.x, b = by >> 8;
    const int pix = by * W + x;
    const float d = den[pix];
    const float s = E1 / (E1 * d + EPS);
    float* p = num + (size_t)b * (C - 1) * HW + pix;
    for (int c = 0; c < C; ++c) p[(size_t)c * HW] *= s;
    den[pix] = 1.0f;
}

// ---------------- launch ----------------

extern "C" void kernel_launch(void* const* d_in, const int* in_sizes, int n_in,
                              void* d_out, int out_size, void* d_ws, size_t ws_size,
                              hipStream_t stream) {
    const float* feat = (const float*)d_in[0];
    const float* flow = (const float*)d_in[1];
    float* out = (float*)d_out;

    const size_t o_counts = 0;
    const size_t o_off    = o_counts + (size_t)NC * 4;
    const size_t o_bsum   = (o_off + (size_t)(NC + 1) * 4 + 15) & ~(size_t)15;
    const size_t o_slot   = (o_bsum + 4096 + 15) & ~(size_t)15;
    const size_t o_lpos   = o_slot + (size_t)S * 4;
    const size_t o_lxy    = (o_lpos + (size_t)S * 4 + 15) & ~(size_t)15;
    const size_t meta_end = o_lxy + (size_t)S * 8;               // ~16.5 MB
    const size_t o_packed = (meta_end + 255) & ~(size_t)255;

    // bf16 main path needs S*64*4 = 128 MB of packed; f32 fallbacks tiered below
    const bool bf16_ok = (o_packed + (size_t)S * 64 * 4) <= ws_size;
    int CC = 0;
    if (!bf16_ok)
        for (int cand = 64; cand >= 16; cand >>= 1)
            if (o_packed + (size_t)S * cand * 4 <= ws_size) { CC = cand; break; }

    if (meta_end <= ws_size) {
        u32*    counts = (u32*)   ((char*)d_ws + o_counts);
        u32*    off    = (u32*)   ((char*)d_ws + o_off);
        u32*    bsum   = (u32*)   ((char*)d_ws + o_bsum);
        u32*    slot   = (u32*)   ((char*)d_ws + o_slot);
        u32*    lpos   = (u32*)   ((char*)d_ws + o_lpos);
        float2* lxy    = (float2*)((char*)d_ws + o_lxy);
        void*   packed = (void*)  ((char*)d_ws + o_packed);

        hipMemsetAsync(counts, 0, (size_t)NC * 4, stream);
        count_kernel<<<B * H, 256, 0, stream>>>(flow, counts);
        scan_blocks<<<NBLK, 256, 0, stream>>>(counts, off, bsum);
        scan_bsum<<<1, 1024, 0, stream>>>(bsum, off);
        scan_add<<<NBLK, 256, 0, stream>>>(off, bsum);
        // fill consumes counts down to zero -> no cursor memset
        fill_kernel<<<B * H, 256, 0, stream>>>(flow, off, counts, slot, lpos, lxy);

        if (bf16_ok) {
            pack128_bf16<<<dim3(W / 64, H, B), 256, 0, stream>>>(
                feat, slot, (u32*)packed);
            gather_cells<<<B * H * (W / 32), 256, 0, stream>>>(
                (const u32*)packed, off, lxy, out);
        } else if (CC) {
            for (int c0 = 0; c0 < C; c0 += CC) {
                pack_kernel<<<dim3(W / 64, H, B), 256, 0, stream>>>(
                    feat, slot, (float*)packed, c0, CC);
                gather_packed<<<dim3(256, B), 256, 0, stream>>>(
                    (const float*)packed, off, lxy, out, c0, CC);
            }
        } else {
            gather_kernel<<<dim3(256, B), 256, 0, stream>>>(feat, off, lpos, lxy, out);
        }
    } else {
        float* num = out;
        float* den = out + (size_t)B * C * HW;
        hipMemsetAsync(d_out, 0, (size_t)out_size * sizeof(float), stream);
        splat_kernel<<<dim3(B * H, CG), 256, 0, stream>>>(feat, flow, num, den);
        normalize_kernel<<<B * H, 256, 0, stream>>>(num, den);
    }
}

// Round 12
// 201.940 us; speedup vs baseline: 1.5235x; 1.5235x over previous
//
#include <hip/hip_runtime.h>

// Softmax splatting (softsplat 'soft', metric==1) via destination-binned GATHER.
// Round 12: round-10 direct pipelined walk (best known) + L3-residency fixes:
// non-temporal OUT stores in gather and non-temporal FEAT loads in pack, so the
// 128 MB bf16 packed buffer stays Infinity-Cache-resident for the gather walk.
// B=8, C=128, H=256, W=256, f32. out = [warped (B,C,H,W) | metric (B,1,H,W)=1]

typedef unsigned int u32;
typedef float f32x4 __attribute__((ext_vector_type(4)));

static constexpr int B = 8, C = 128, H = 256, W = 256;
static constexpr int HW = H * W;
static constexpr int PH = H + 1, PW = W + 1;         // padded floor-cell grid
static constexpr int NC = B * PH * PW;               // 528392 cells
static constexpr int S  = B * HW;                    // 524288 sources
static constexpr u32 SM1 = (u32)(S - 1);
static constexpr float E1  = 2.7182818284590452354f; // exp(1) (metric == 1)
static constexpr float EPS = 1e-7f;
static constexpr int CHUNK = 1024;
static constexpr int NBLK  = (NC + CHUNK - 1) / CHUNK;  // 517

__device__ __forceinline__ u32 bf16rne(float f) {
    const u32 u = __float_as_uint(f);
    return (u + 0x7fffu + ((u >> 16) & 1u)) >> 16;
}

// ---------------- binning ----------------

__global__ __launch_bounds__(256) void count_kernel(const float* __restrict__ flow,
                                                    u32* __restrict__ counts)
{
    const int x = threadIdx.x, by = blockIdx.x, b = by >> 8, y = by & 255;
    const float fx = (float)x + flow[(b * 2) * HW + y * W + x];
    const float fy = (float)y + flow[(b * 2 + 1) * HW + y * W + x];
    const int ix0 = (int)floorf(fx), iy0 = (int)floorf(fy);
    if (ix0 >= -1 && ix0 < W && iy0 >= -1 && iy0 < H)
        atomicAdd(&counts[(b * PH + iy0 + 1) * PW + (ix0 + 1)], 1u);
}

__global__ __launch_bounds__(256) void scan_blocks(const u32* __restrict__ in,
                                                   u32* __restrict__ out,
                                                   u32* __restrict__ bsum)
{
    __shared__ u32 sd[256];
    const int tid = threadIdx.x;
    const int base = blockIdx.x * CHUNK + tid * 4;
    u32 v0 = 0, v1 = 0, v2 = 0, v3 = 0;
    if (base + 3 < NC) {
        const uint4 q = *(const uint4*)(in + base);
        v0 = q.x; v1 = q.y; v2 = q.z; v3 = q.w;
    } else {
        if (base     < NC) v0 = in[base];
        if (base + 1 < NC) v1 = in[base + 1];
        if (base + 2 < NC) v2 = in[base + 2];
    }
    const u32 t = v0 + v1 + v2 + v3;
    sd[tid] = t; __syncthreads();
    for (int o = 1; o < 256; o <<= 1) {
        const u32 a = (tid >= o) ? sd[tid - o] : 0u;
        __syncthreads();
        sd[tid] += a;
        __syncthreads();
    }
    const u32 excl = sd[tid] - t;
    if (base + 3 < NC) {
        uint4 q; q.x = excl; q.y = excl + v0; q.z = excl + v0 + v1; q.w = excl + v0 + v1 + v2;
        *(uint4*)(out + base) = q;
    } else {
        if (base     < NC) out[base]     = excl;
        if (base + 1 < NC) out[base + 1] = excl + v0;
        if (base + 2 < NC) out[base + 2] = excl + v0 + v1;
    }
    if (tid == 255) bsum[blockIdx.x] = sd[255];
}

__global__ __launch_bounds__(1024) void scan_bsum(u32* __restrict__ bsum,
                                                  u32* __restrict__ off)
{
    __shared__ u32 sd[1024];
    const int tid = threadIdx.x;
    const u32 v = (tid < NBLK) ? bsum[tid] : 0u;
    sd[tid] = v; __syncthreads();
    for (int o = 1; o < 1024; o <<= 1) {
        const u32 a = (tid >= o) ? sd[tid - o] : 0u;
        __syncthreads();
        sd[tid] += a;
        __syncthreads();
    }
    if (tid < NBLK) bsum[tid] = sd[tid] - v;
    if (tid == 1023) off[NC] = sd[1023];
}

__global__ __launch_bounds__(256) void scan_add(u32* __restrict__ off,
                                                const u32* __restrict__ bsum)
{
    const u32 add = bsum[blockIdx.x];
    if (add == 0) return;
    const int base = blockIdx.x * CHUNK + threadIdx.x * 4;
    if (base + 3 < NC) {
        uint4 q = *(uint4*)(off + base);
        q.x += add; q.y += add; q.z += add; q.w += add;
        *(uint4*)(off + base) = q;
    } else {
        for (int k = 0; k < 4; ++k)
            if (base + k < NC) off[base + k] += add;
    }
}

// fill claims slots by DECREMENTING counts (no cursor memset needed)
__global__ __launch_bounds__(256) void fill_kernel(const float* __restrict__ flow,
                                                   const u32* __restrict__ off,
                                                   u32* __restrict__ cnt,
                                                   u32* __restrict__ slot_of_src,
                                                   u32* __restrict__ lpos,
                                                   float2* __restrict__ lxy)
{
    const int x = threadIdx.x, by = blockIdx.x, b = by >> 8, y = by & 255;
    const float fx = (float)x + flow[(b * 2) * HW + y * W + x];
    const float fy = (float)y + flow[(b * 2 + 1) * HW + y * W + x];
    const int ix0 = (int)floorf(fx), iy0 = (int)floorf(fy);
    const int src = b * HW + y * W + x;
    if (ix0 >= -1 && ix0 < W && iy0 >= -1 && iy0 < H) {
        const int cell = (b * PH + iy0 + 1) * PW + (ix0 + 1);
        const u32 old = atomicSub(&cnt[cell], 1u);
        const u32 slot = off[cell] + old - 1u;
        slot_of_src[src] = slot;
        lpos[slot] = (u32)(y * W + x);
        lxy[slot]  = make_float2(fx, fy);
    } else {
        slot_of_src[src] = 0xFFFFFFFFu;
    }
}

// ---------------- pack (bf16): u16 LDS tile, (c, c+64) pair -> one u32 ----------------
// feat is read ONCE -> non-temporal loads keep it from evicting `packed` in L3.

__global__ __launch_bounds__(256) void pack128_bf16(const float* __restrict__ feat,
                                                    const u32* __restrict__ slot_of_src,
                                                    u32* __restrict__ packed)
{
    __shared__ unsigned short lds[64 * 129];   // 16.5 KB: [pix][ch] bf16
    const int x0 = blockIdx.x * 64, y = blockIdx.y, b = blockIdx.z;
    const int tid = threadIdx.x;
    const float* fbase = feat + (size_t)(b * C) * HW + y * W + x0;
    for (int idx = tid; idx < 128 * 16; idx += 256) {
        const int cc = idx >> 4, i4 = (idx & 15) * 4;
        const f32x4 v = __builtin_nontemporal_load(
            (const f32x4*)(fbase + (size_t)cc * HW + i4));
        lds[(i4 + 0) * 129 + cc] = (unsigned short)bf16rne(v.x);
        lds[(i4 + 1) * 129 + cc] = (unsigned short)bf16rne(v.y);
        lds[(i4 + 2) * 129 + cc] = (unsigned short)bf16rne(v.z);
        lds[(i4 + 3) * 129 + cc] = (unsigned short)bf16rne(v.w);
    }
    __syncthreads();
    const int wave = tid >> 6, lane = tid & 63;
    const u32* sp = slot_of_src + (size_t)b * HW + y * W + x0;
    for (int p = wave * 16; p < wave * 16 + 16; ++p) {
        const u32 s = sp[p];
        if (s == 0xFFFFFFFFu) continue;
        const u32 lo = (u32)lds[p * 129 + lane];
        const u32 hi = (u32)lds[p * 129 + 64 + lane];
        packed[(size_t)s * 64 + lane] = lo | (hi << 16);
    }
}

// generic f32 pack (fallback path, CC<128, linear layout)
__global__ __launch_bounds__(256) void pack_kernel(const float* __restrict__ feat,
                                                   const u32* __restrict__ slot_of_src,
                                                   float* __restrict__ packed,
                                                   int c0, int CC)
{
    __shared__ float lds[64 * 129];
    const int x0 = blockIdx.x * 64, y = blockIdx.y, b = blockIdx.z;
    const int tid = threadIdx.x;
    const float* fbase = feat + (size_t)(b * C + c0) * HW + y * W + x0;
    const int n = CC * 64;
    for (int idx = tid; idx < n; idx += 256) {
        const int cc = idx >> 6, i = idx & 63;
        lds[i * 129 + cc] = fbase[(size_t)cc * HW + i];
    }
    __syncthreads();
    const int wave = tid >> 6, lane = tid & 63;
    const u32* sp = slot_of_src + (size_t)b * HW + y * W + x0;
    for (int p = wave * 16; p < wave * 16 + 16; ++p) {
        const u32 s = sp[p];
        if (s == 0xFFFFFFFFu) continue;
        float* dst = packed + (size_t)s * CC;
        for (int j = lane; j < CC; j += 64)
            dst[j] = lds[p * 129 + j];
    }
}

// ---------------- 8-pixel-wave gather: depth-2 cross-cell + inner-run pipeline ----------------
// Round-10 structure. OUT writes are non-temporal (streaming) so they don't
// evict the L3-resident packed buffer.

#define KM1(K) ((K) >= 1 ? (K) - 1 : 0)
#define KK(K)  ((K) <= 7 ? (K) : 0)

#define ACCUM(K, w0, w1, dx_, dy_)                                             \
    if ((K) >= 1) {                                                            \
        acc0[KM1(K)] = fmaf(w0, dx_, acc0[KM1(K)]);                            \
        acc1[KM1(K)] = fmaf(w0, dy_, acc1[KM1(K)]);                            \
        den [KM1(K)] += w0;                                                    \
    }                                                                          \
    if ((K) <= 7) {                                                            \
        acc0[KK(K)] = fmaf(w1, dx_, acc0[KK(K)]);                              \
        acc1[KK(K)] = fmaf(w1, dy_, acc1[KK(K)]);                              \
        den [KK(K)] += w1;                                                     \
    }

#define PROC(K, xy, du)                                                        \
    {                                                                          \
        const float fr = (xy).x - (float)(oxw - 1 + (K));                      \
        const float wy = 1.f - fabsf((xy).y - foy);                            \
        const float w0 = (1.f - fr) * wy, w1 = fr * wy;                        \
        const float dx_ = __uint_as_float((du) << 16);                         \
        const float dy_ = __uint_as_float((du) & 0xffff0000u);                 \
        ACCUM(K, w0, w1, dx_, dy_)                                             \
    }

// run with inner software pipeline (first entry comes prefetched in xy_c/du_c)
#define RUN(K, bnd, xy_c, du_c)                                                \
    if (bnd[K] < bnd[(K) + 1]) {                                               \
        PROC(K, xy_c, du_c)                                                    \
        u32 i = bnd[K] + 1;                                                    \
        if (i < bnd[(K) + 1]) {                                                \
            float2 xyp = lxy[i];                                               \
            u32    dup = pk[(size_t)i * 64 + lane];                            \
            for (++i; i < bnd[(K) + 1]; ++i) {                                 \
                const float2 xyn = lxy[i];                                     \
                const u32    dun = pk[(size_t)i * 64 + lane];                  \
                PROC(K, xyp, dup)                                              \
                xyp = xyn; dup = dun;                                          \
            }                                                                  \
            PROC(K, xyp, dup)                                                  \
        }                                                                      \
    }

#define BIA(K) bndA[(K) <= 9 ? (K) : 9]
#define BIB(K) bndB[(K) <= 9 ? (K) : 9]

#define STAGE(K)                                                               \
    {                                                                          \
        const u32 nAi = BIA((K) + 2) < SM1 ? BIA((K) + 2) : SM1;               \
        const u32 nBi = BIB((K) + 2) < SM1 ? BIB((K) + 2) : SM1;               \
        const float2 xyA_n = lxy[nAi]; const u32 duA_n = pk[(size_t)nAi * 64 + lane]; \
        const float2 xyB_n = lxy[nBi]; const u32 duB_n = pk[(size_t)nBi * 64 + lane]; \
        RUN(K, bndA, xyA_c, duA_c)                                             \
        RUN(K, bndB, xyB_c, duB_c)                                             \
        xyA_c = xyA_m; duA_c = duA_m; xyA_m = xyA_n; duA_m = duA_n;            \
        xyB_c = xyB_m; duB_c = duB_m; xyB_m = xyB_n; duB_m = duB_n;            \
    }

__global__ __launch_bounds__(256) void gather_cells(
    const u32* __restrict__ pk, const u32* __restrict__ off,
    const float2* __restrict__ lxy, float* __restrict__ out)
{
    __shared__ float lds[32 * 65];    // 8.5 KB padded transpose tile
    __shared__ float ldsden[32];
    const int tid = threadIdx.x, wv = tid >> 6, lane = tid & 63;
    // XCD-bijective swizzle: 16384 blocks = 8 XCDs x 2048; each XCD owns one
    // batch (8 xseg x 256 rows), rows fastest -> cell-row reuse in that XCD's L2.
    const u32 bid = blockIdx.x;
    const u32 swz = (bid & 7u) * 2048u + (bid >> 3);
    const int b    = (int)(swz >> 11);
    const int xseg = (int)((swz >> 8) & 7u);
    const int row  = (int)(swz & 255u);
    const int ox0  = xseg * 32;            // block's first output x (32 px/block)
    const int oxw  = ox0 + wv * 8;         // this wave's first output x (8 px/wave)
    const float foy = (float)row;

    float acc0[8], acc1[8], den[8];
    #pragma unroll
    for (int k = 0; k < 8; ++k) { acc0[k] = 0.f; acc1[k] = 0.f; den[k] = 0.f; }

    // wave-uniform boundary base -> scalar loads for the 20 bnd values
    const u32 rbu = (u32)__builtin_amdgcn_readfirstlane(
        (int)((u32)((b * PH + row) * PW + oxw)));
    u32 bndA[10], bndB[10];
    #pragma unroll
    for (int q = 0; q < 10; ++q) {
        bndA[q] = off[rbu + q];        // cell-row above (padded row = row)
        bndB[q] = off[rbu + PW + q];   // cell-row at    (padded row = row+1)
    }

    // pipeline prologue: first entries of cells 0 (cur) and 1 (mid)
    float2 xyA_c, xyA_m, xyB_c, xyB_m;
    u32 duA_c, duA_m, duB_c, duB_m;
    {
        const u32 a0 = bndA[0] < SM1 ? bndA[0] : SM1;
        const u32 b0 = bndB[0] < SM1 ? bndB[0] : SM1;
        const u32 a1 = bndA[1] < SM1 ? bndA[1] : SM1;
        const u32 b1 = bndB[1] < SM1 ? bndB[1] : SM1;
        xyA_c = lxy[a0]; duA_c = pk[(size_t)a0 * 64 + lane];
        xyB_c = lxy[b0]; duB_c = pk[(size_t)b0 * 64 + lane];
        xyA_m = lxy[a1]; duA_m = pk[(size_t)a1 * 64 + lane];
        xyB_m = lxy[b1]; duB_m = pk[(size_t)b1 * 64 + lane];
    }

    STAGE(0) STAGE(1) STAGE(2) STAGE(3) STAGE(4)
    STAGE(5) STAGE(6) STAGE(7) STAGE(8)

    // ---- epilogue round A: channels 0..63 (acc0, c == lane) ----
    #pragma unroll
    for (int k = 0; k < 8; ++k) {
        const int p = wv * 8 + k;
        lds[p * 65 + lane] = acc0[k];
        if (lane == 0) ldsden[p] = den[k];
    }
    __syncthreads();
    {
        const int px = tid & 31, cslot = tid >> 5;
        const float dn = ldsden[px];
        const float s  = E1 / (E1 * dn + EPS);
        #pragma unroll
        for (int j = 0; j < 8; ++j) {
            const int c = cslot * 8 + j;
            __builtin_nontemporal_store(
                lds[px * 65 + c] * s,
                &out[(size_t)(b * C + c) * HW + (size_t)row * W + ox0 + px]);
        }
    }
    __syncthreads();
    // ---- epilogue round B: channels 64..127 (acc1) ----
    #pragma unroll
    for (int k = 0; k < 8; ++k) {
        const int p = wv * 8 + k;
        lds[p * 65 + lane] = acc1[k];
    }
    __syncthreads();
    {
        const int px = tid & 31, cslot = tid >> 5;
        const float dn = ldsden[px];
        const float s  = E1 / (E1 * dn + EPS);
        #pragma unroll
        for (int j = 0; j < 8; ++j) {
            const int c = cslot * 8 + j;
            __builtin_nontemporal_store(
                lds[px * 65 + c] * s,
                &out[(size_t)(b * C + 64 + c) * HW + (size_t)row * W + ox0 + px]);
        }
    }
    if (tid < 32)
        __builtin_nontemporal_store(
            1.0f,
            &out[(size_t)(B * C) * HW + (size_t)b * HW + (size_t)row * W + ox0 + tid]);
}

// ---------------- fallback: per-thread gather from f32 packed (CC<128) ----------------

__global__ __launch_bounds__(256) void gather_packed(
    const float* __restrict__ packed, const u32* __restrict__ off,
    const float2* __restrict__ lxy, float* __restrict__ out, int c0, int CC)
{
    const int t = threadIdx.x;
    const int tile = blockIdx.x, b = blockIdx.y;
    const int ox = ((tile & 15) << 4) | (t & 15);
    const int oy = ((tile >> 4) << 4) | (t >> 4);
    const int opix = oy * W + ox;
    const u32 rb0 = (u32)((b * PH + oy) * PW + ox);
    const u32 s0 = off[rb0],      e0 = off[rb0 + 2];
    const u32 s1 = off[rb0 + PW], e1 = off[rb0 + PW + 2];
    const float fox = (float)ox, foy = (float)oy;
    float scale = 0.f;
    for (int ch = 0; ch < CC; ch += 16) {
        float acc[16];
        #pragma unroll
        for (int c = 0; c < 16; ++c) acc[c] = 0.f;
        float den = 0.f;
        for (int rr = 0; rr < 2; ++rr) {
            u32 i = rr ? s1 : s0;
            const u32 e = rr ? e1 : e0;
            for (; i < e; ++i) {
                const float2 xy = lxy[i];
                const float w = (1.f - fabsf(xy.x - fox)) * (1.f - fabsf(xy.y - foy));
                den += w;
                const float4* ep = (const float4*)(packed + (size_t)i * CC + ch);
                const float4 q0 = ep[0], q1 = ep[1], q2 = ep[2], q3 = ep[3];
                acc[ 0] = fmaf(w, q0.x, acc[ 0]); acc[ 1] = fmaf(w, q0.y, acc[ 1]);
                acc[ 2] = fmaf(w, q0.z, acc[ 2]); acc[ 3] = fmaf(w, q0.w, acc[ 3]);
                acc[ 4] = fmaf(w, q1.x, acc[ 4]); acc[ 5] = fmaf(w, q1.y, acc[ 5]);
                acc[ 6] = fmaf(w, q1.z, acc[ 6]); acc[ 7] = fmaf(w, q1.w, acc[ 7]);
                acc[ 8] = fmaf(w, q2.x, acc[ 8]); acc[ 9] = fmaf(w, q2.y, acc[ 9]);
                acc[10] = fmaf(w, q2.z, acc[10]); acc[11] = fmaf(w, q2.w, acc[11]);
                acc[12] = fmaf(w, q3.x, acc[12]); acc[13] = fmaf(w, q3.y, acc[13]);
                acc[14] = fmaf(w, q3.z, acc[14]); acc[15] = fmaf(w, q3.w, acc[15]);
            }
        }
        if (ch == 0) scale = E1 / (E1 * den + EPS);
        float* op = out + (size_t)(b * C + c0 + ch) * HW + opix;
        #pragma unroll
        for (int c = 0; c < 16; ++c) op[(size_t)c * HW] = acc[c] * scale;
    }
    if (c0 == 0)
        out[(size_t)(B * C) * HW + (size_t)b * HW + opix] = 1.0f;
}

// ---------------- fallback: planar gather ----------------

__global__ __launch_bounds__(256) void gather_kernel(
    const float* __restrict__ feat, const u32* __restrict__ off,
    const u32* __restrict__ lpos, const float2* __restrict__ lxy,
    float* __restrict__ out)
{
    const int t = threadIdx.x;
    const int tile = blockIdx.x, b = blockIdx.y;
    const int ox = ((tile & 15) << 4) | (t & 15);
    const int oy = ((tile >> 4) << 4) | (t >> 4);
    const int opix = oy * W + ox;
    const u32 rb0 = (u32)((b * PH + oy) * PW + ox);
    const u32 s0 = off[rb0],      e0 = off[rb0 + 2];
    const u32 s1 = off[rb0 + PW], e1 = off[rb0 + PW + 2];
    const float fox = (float)ox, foy = (float)oy;
    float den = 0.f;
    for (int rr = 0; rr < 2; ++rr) {
        u32 i = rr ? s1 : s0;
        const u32 e = rr ? e1 : e0;
        for (; i < e; ++i) {
            const float2 xy = lxy[i];
            den += (1.f - fabsf(xy.x - fox)) * (1.f - fabsf(xy.y - foy));
        }
    }
    const float scale = E1 / (E1 * den + EPS);
    for (int ch = 0; ch < C; ch += 16) {
        float acc[16];
        #pragma unroll
        for (int c = 0; c < 16; ++c) acc[c] = 0.f;
        const float* fb = feat + (size_t)(b * C + ch) * HW;
        for (int rr = 0; rr < 2; ++rr) {
            u32 i = rr ? s1 : s0;
            const u32 e = rr ? e1 : e0;
            for (; i < e; ++i) {
                const float2 xy = lxy[i];
                const float w = (1.f - fabsf(xy.x - fox)) * (1.f - fabsf(xy.y - foy));
                const float* fp = fb + lpos[i];
                #pragma unroll
                for (int c = 0; c < 16; ++c)
                    acc[c] = fmaf(w, fp[(size_t)c * HW], acc[c]);
            }
        }
        float* op = out + (size_t)(b * C + ch) * HW + opix;
        #pragma unroll
        for (int c = 0; c < 16; ++c) op[(size_t)c * HW] = acc[c] * scale;
    }
    out[(size_t)(B * C) * HW + (size_t)b * HW + opix] = 1.0f;
}

// ---------------- fallback: round-1 atomic path ----------------

static constexpr int CG = 8, CPG = C / CG;

__global__ __launch_bounds__(256) void splat_kernel(
    const float* __restrict__ feat, const float* __restrict__ flow,
    float* __restrict__ num, float* __restrict__ den)
{
    const int x = threadIdx.x, by = blockIdx.x, b = by >> 8, y = by & (H - 1);
    const int cg = blockIdx.y;
    const float fx = (float)x + flow[(b * 2 * H + y) * W + x];
    const float fy = (float)y + flow[((b * 2 + 1) * H + y) * W + x];
    const float x0f = floorf(fx), y0f = floorf(fy);
    const int ix0 = (int)x0f, iy0 = (int)y0f;
    const float ax = fx - x0f, ay = fy - y0f;
    const float w00 = (1.f - ax) * (1.f - ay), w10 = ax * (1.f - ay);
    const float w01 = (1.f - ax) * ay,         w11 = ax * ay;
    const bool vx0 = (unsigned)ix0       < (unsigned)W;
    const bool vx1 = (unsigned)(ix0 + 1) < (unsigned)W;
    const bool vy0 = (unsigned)iy0       < (unsigned)H;
    const bool vy1 = (unsigned)(iy0 + 1) < (unsigned)H;
    const bool v00 = vx0 && vy0, v10 = vx1 && vy0;
    const bool v01 = vx0 && vy1, v11 = vx1 && vy1;
    const int t00 = iy0 * W + ix0, t01 = t00 + W;
    if (cg == 0) {
        float* dn = den + b * HW;
        if (v00) atomicAdd(dn + t00,     w00);
        if (v10) atomicAdd(dn + t00 + 1, w10);
        if (v01) atomicAdd(dn + t01,     w01);
        if (v11) atomicAdd(dn + t01 + 1, w11);
    }
    const int c0 = cg * CPG;
    const float* fp = feat + ((size_t)(b * C + c0)) * HW + y * W + x;
    float*       np = num  + ((size_t)(b * C + c0)) * HW;
    for (int c = 0; c < CPG; ++c) {
        const float v = fp[(size_t)c * HW];
        float* nc = np + (size_t)c * HW;
        if (v00) atomicAdd(nc + t00,     v * w00);
        if (v10) atomicAdd(nc + t00 + 1, v * w10);
        if (v01) atomicAdd(nc + t01,     v * w01);
        if (v11) atomicAdd(nc + t01 + 1, v * w11);
    }
}

__global__ __launch_bounds__(256) void normalize_kernel(float* __restrict__ num,
                                                        float* __restrict__ den)
{
    const int x = threadIdx.x, by = blockIdx.x, b = by >> 8;
    const int pix = by * W + x;
    const float d = den[pix];
    const float s = E1 / (E1 * d + EPS);
    float* p = num + (size_t)b * (C - 1) * HW + pix;
    for (int c = 0; c < C; ++c) p[(size_t)c * HW] *= s;
    den[pix] = 1.0f;
}

// ---------------- launch ----------------

extern "C" void kernel_launch(void* const* d_in, const int* in_sizes, int n_in,
                              void* d_out, int out_size, void* d_ws, size_t ws_size,
                              hipStream_t stream) {
    const float* feat = (const float*)d_in[0];
    const float* flow = (const float*)d_in[1];
    float* out = (float*)d_out;

    const size_t o_counts = 0;
    const size_t o_off    = o_counts + (size_t)NC * 4;
    const size_t o_bsum   = (o_off + (size_t)(NC + 1) * 4 + 15) & ~(size_t)15;
    const size_t o_slot   = (o_bsum + 4096 + 15) & ~(size_t)15;
    const size_t o_lpos   = o_slot + (size_t)S * 4;
    const size_t o_lxy    = (o_lpos + (size_t)S * 4 + 15) & ~(size_t)15;
    const size_t meta_end = o_lxy + (size_t)S * 8;               // ~16.5 MB
    const size_t o_packed = (meta_end + 255) & ~(size_t)255;

    // bf16 main path needs S*64*4 = 128 MB of packed; f32 fallbacks tiered below
    const bool bf16_ok = (o_packed + (size_t)S * 64 * 4) <= ws_size;
    int CC = 0;
    if (!bf16_ok)
        for (int cand = 64; cand >= 16; cand >>= 1)
            if (o_packed + (size_t)S * cand * 4 <= ws_size) { CC = cand; break; }

    if (meta_end <= ws_size) {
        u32*    counts = (u32*)   ((char*)d_ws + o_counts);
        u32*    off    = (u32*)   ((char*)d_ws + o_off);
        u32*    bsum   = (u32*)   ((char*)d_ws + o_bsum);
        u32*    slot   = (u32*)   ((char*)d_ws + o_slot);
        u32*    lpos   = (u32*)   ((char*)d_ws + o_lpos);
        float2* lxy    = (float2*)((char*)d_ws + o_lxy);
        void*   packed = (void*)  ((char*)d_ws + o_packed);

        hipMemsetAsync(counts, 0, (size_t)NC * 4, stream);
        count_kernel<<<B * H, 256, 0, stream>>>(flow, counts);
        scan_blocks<<<NBLK, 256, 0, stream>>>(counts, off, bsum);
        scan_bsum<<<1, 1024, 0, stream>>>(bsum, off);
        scan_add<<<NBLK, 256, 0, stream>>>(off, bsum);
        // fill consumes counts down to zero -> no cursor memset
        fill_kernel<<<B * H, 256, 0, stream>>>(flow, off, counts, slot, lpos, lxy);

        if (bf16_ok) {
            pack128_bf16<<<dim3(W / 64, H, B), 256, 0, stream>>>(
                feat, slot, (u32*)packed);
            gather_cells<<<B * H * (W / 32), 256, 0, stream>>>(
                (const u32*)packed, off, lxy, out);
        } else if (CC) {
            for (int c0 = 0; c0 < C; c0 += CC) {
                pack_kernel<<<dim3(W / 64, H, B), 256, 0, stream>>>(
                    feat, slot, (float*)packed, c0, CC);
                gather_packed<<<dim3(256, B), 256, 0, stream>>>(
                    (const float*)packed, off, lxy, out, c0, CC);
            }
        } else {
            gather_kernel<<<dim3(256, B), 256, 0, stream>>>(feat, off, lpos, lxy, out);
        }
    } else {
        float* num = out;
        float* den = out + (size_t)B * C * HW;
        hipMemsetAsync(d_out, 0, (size_t)out_size * sizeof(float), stream);
        splat_kernel<<<dim3(B * H, CG), 256, 0, stream>>>(feat, flow, num, den);
        normalize_kernel<<<B * H, 256, 0, stream>>>(num, den);
    }
}

// Round 13
// 187.070 us; speedup vs baseline: 1.6446x; 1.0795x over previous
//
#include <hip/hip_runtime.h>

// Softmax splatting (softsplat 'soft', metric==1) via destination-binned GATHER.
// Round 13: prologue consolidation — fill fused into pack (slot claim inside the
// pack block), scan_add dropped in main path (consumers add bsum[chunk]).
// Retains r12: bf16 L3-resident packed entries, NT feat loads, NT out stores,
// depth-2 dual-row pipelined per-cell walk with static accumulator indices.
// B=8, C=128, H=256, W=256, f32. out = [warped (B,C,H,W) | metric (B,1,H,W)=1]

typedef unsigned int u32;
typedef float f32x4 __attribute__((ext_vector_type(4)));

static constexpr int B = 8, C = 128, H = 256, W = 256;
static constexpr int HW = H * W;
static constexpr int PH = H + 1, PW = W + 1;         // padded floor-cell grid
static constexpr int NC = B * PH * PW;               // 528392 cells
static constexpr int S  = B * HW;                    // 524288 sources
static constexpr u32 SM1 = (u32)(S - 1);
static constexpr float E1  = 2.7182818284590452354f; // exp(1) (metric == 1)
static constexpr float EPS = 1e-7f;
static constexpr int CHUNK = 1024;
static constexpr int NBLK  = (NC + CHUNK - 1) / CHUNK;  // 517
static constexpr int LASTCH = NC / CHUNK;            // chunk containing index NC (516)

__device__ __forceinline__ u32 bf16rne(float f) {
    const u32 u = __float_as_uint(f);
    return (u + 0x7fffu + ((u >> 16) & 1u)) >> 16;
}

// ---------------- binning ----------------

__global__ __launch_bounds__(256) void count_kernel(const float* __restrict__ flow,
                                                    u32* __restrict__ counts)
{
    const int x = threadIdx.x, by = blockIdx.x, b = by >> 8, y = by & 255;
    const float fx = (float)x + flow[(b * 2) * HW + y * W + x];
    const float fy = (float)y + flow[(b * 2 + 1) * HW + y * W + x];
    const int ix0 = (int)floorf(fx), iy0 = (int)floorf(fy);
    if (ix0 >= -1 && ix0 < W && iy0 >= -1 && iy0 < H)
        atomicAdd(&counts[(b * PH + iy0 + 1) * PW + (ix0 + 1)], 1u);
}

__global__ __launch_bounds__(256) void scan_blocks(const u32* __restrict__ in,
                                                   u32* __restrict__ out,
                                                   u32* __restrict__ bsum)
{
    __shared__ u32 sd[256];
    const int tid = threadIdx.x;
    const int base = blockIdx.x * CHUNK + tid * 4;
    u32 v0 = 0, v1 = 0, v2 = 0, v3 = 0;
    if (base + 3 < NC) {
        const uint4 q = *(const uint4*)(in + base);
        v0 = q.x; v1 = q.y; v2 = q.z; v3 = q.w;
    } else {
        if (base     < NC) v0 = in[base];
        if (base + 1 < NC) v1 = in[base + 1];
        if (base + 2 < NC) v2 = in[base + 2];
    }
    const u32 t = v0 + v1 + v2 + v3;
    sd[tid] = t; __syncthreads();
    for (int o = 1; o < 256; o <<= 1) {
        const u32 a = (tid >= o) ? sd[tid - o] : 0u;
        __syncthreads();
        sd[tid] += a;
        __syncthreads();
    }
    const u32 excl = sd[tid] - t;
    if (base + 3 < NC) {
        uint4 q; q.x = excl; q.y = excl + v0; q.z = excl + v0 + v1; q.w = excl + v0 + v1 + v2;
        *(uint4*)(out + base) = q;
    } else {
        if (base     < NC) out[base]     = excl;
        if (base + 1 < NC) out[base + 1] = excl + v0;
        if (base + 2 < NC) out[base + 2] = excl + v0 + v1;
    }
    if (tid == 255) bsum[blockIdx.x] = sd[255];
}

// bsum -> exclusive scan; off[NC] set so that off[NC] + bsum[LASTCH] == total
__global__ __launch_bounds__(1024) void scan_bsum(u32* __restrict__ bsum,
                                                  u32* __restrict__ off)
{
    __shared__ u32 sd[1024];
    const int tid = threadIdx.x;
    const u32 v = (tid < NBLK) ? bsum[tid] : 0u;
    sd[tid] = v; __syncthreads();
    for (int o = 1; o < 1024; o <<= 1) {
        const u32 a = (tid >= o) ? sd[tid - o] : 0u;
        __syncthreads();
        sd[tid] += a;
        __syncthreads();
    }
    if (tid < NBLK) bsum[tid] = sd[tid] - v;
    if (tid == LASTCH) off[NC] = sd[1023] - (sd[tid] - v);
}

// fallback-path only: bake bsum into off (and fix off[NC] to plain total)
__global__ __launch_bounds__(256) void scan_add(u32* __restrict__ off,
                                                const u32* __restrict__ bsum)
{
    const u32 add = bsum[blockIdx.x];
    if (blockIdx.x == NBLK - 1 && threadIdx.x == 255) off[NC] += bsum[LASTCH];
    if (add == 0) return;
    const int base = blockIdx.x * CHUNK + threadIdx.x * 4;
    if (base + 3 < NC) {
        uint4 q = *(uint4*)(off + base);
        q.x += add; q.y += add; q.z += add; q.w += add;
        *(uint4*)(off + base) = q;
    } else {
        for (int k = 0; k < 4; ++k)
            if (base + k < NC) off[base + k] += add;
    }
}

// fallback-path fill (after scan_add; claims slots by decrementing counts)
__global__ __launch_bounds__(256) void fill_kernel(const float* __restrict__ flow,
                                                   const u32* __restrict__ off,
                                                   u32* __restrict__ cnt,
                                                   u32* __restrict__ slot_of_src,
                                                   u32* __restrict__ lpos,
                                                   float2* __restrict__ lxy)
{
    const int x = threadIdx.x, by = blockIdx.x, b = by >> 8, y = by & 255;
    const float fx = (float)x + flow[(b * 2) * HW + y * W + x];
    const float fy = (float)y + flow[(b * 2 + 1) * HW + y * W + x];
    const int ix0 = (int)floorf(fx), iy0 = (int)floorf(fy);
    const int src = b * HW + y * W + x;
    if (ix0 >= -1 && ix0 < W && iy0 >= -1 && iy0 < H) {
        const int cell = (b * PH + iy0 + 1) * PW + (ix0 + 1);
        const u32 old = atomicSub(&cnt[cell], 1u);
        const u32 slot = off[cell] + old - 1u;
        slot_of_src[src] = slot;
        lpos[slot] = (u32)(y * W + x);
        lxy[slot]  = make_float2(fx, fy);
    } else {
        slot_of_src[src] = 0xFFFFFFFFu;
    }
}

// ---------------- fused pack (bf16): slot claim + lxy write + pack ----------------
// Block owns 64 source pixels. Wave 0's 64 lanes compute flow/cell, claim slots
// (atomicSub on counts; final offset = off[cell] + bsum[cell>>10]) and write lxy.
// All 4 waves stage the 128-ch feat tile (NT f32x4 loads) as bf16 into LDS, then
// write each in-range pixel's 256B packed entry (one u32 per lane).

__global__ __launch_bounds__(256) void pack128_fused(const float* __restrict__ feat,
                                                     const float* __restrict__ flow,
                                                     const u32* __restrict__ off,
                                                     const u32* __restrict__ bsum,
                                                     u32* __restrict__ cnt,
                                                     u32* __restrict__ packed,
                                                     float2* __restrict__ lxy)
{
    __shared__ unsigned short lds[64 * 129];   // 16.5 KB: [pix][ch] bf16
    __shared__ u32 sslot[64];
    const int x0 = blockIdx.x * 64, y = blockIdx.y, b = blockIdx.z;
    const int tid = threadIdx.x;

    if (tid < 64) {   // slot claim for this block's 64 source pixels
        const int x = x0 + tid;
        const float fx = (float)x + flow[(b * 2) * HW + y * W + x];
        const float fy = (float)y + flow[(b * 2 + 1) * HW + y * W + x];
        const int ix0 = (int)floorf(fx), iy0 = (int)floorf(fy);
        if (ix0 >= -1 && ix0 < W && iy0 >= -1 && iy0 < H) {
            const int cell = (b * PH + iy0 + 1) * PW + (ix0 + 1);
            const u32 old = atomicSub(&cnt[cell], 1u);
            const u32 slot = off[cell] + bsum[cell >> 10] + old - 1u;
            sslot[tid] = slot;
            lxy[slot]  = make_float2(fx, fy);
        } else {
            sslot[tid] = 0xFFFFFFFFu;
        }
    }

    const float* fbase = feat + (size_t)(b * C) * HW + y * W + x0;
    for (int idx = tid; idx < 128 * 16; idx += 256) {
        const int cc = idx >> 4, i4 = (idx & 15) * 4;
        const f32x4 v = __builtin_nontemporal_load(
            (const f32x4*)(fbase + (size_t)cc * HW + i4));
        lds[(i4 + 0) * 129 + cc] = (unsigned short)bf16rne(v.x);
        lds[(i4 + 1) * 129 + cc] = (unsigned short)bf16rne(v.y);
        lds[(i4 + 2) * 129 + cc] = (unsigned short)bf16rne(v.z);
        lds[(i4 + 3) * 129 + cc] = (unsigned short)bf16rne(v.w);
    }
    __syncthreads();

    const int wave = tid >> 6, lane = tid & 63;
    for (int p = wave * 16; p < wave * 16 + 16; ++p) {
        const u32 s = sslot[p];
        if (s == 0xFFFFFFFFu) continue;
        const u32 lo = (u32)lds[p * 129 + lane];
        const u32 hi = (u32)lds[p * 129 + 64 + lane];
        packed[(size_t)s * 64 + lane] = lo | (hi << 16);
    }
}

// generic f32 pack (fallback path, CC<128, linear layout; needs fill's slot map)
__global__ __launch_bounds__(256) void pack_kernel(const float* __restrict__ feat,
                                                   const u32* __restrict__ slot_of_src,
                                                   float* __restrict__ packed,
                                                   int c0, int CC)
{
    __shared__ float lds[64 * 129];
    const int x0 = blockIdx.x * 64, y = blockIdx.y, b = blockIdx.z;
    const int tid = threadIdx.x;
    const float* fbase = feat + (size_t)(b * C + c0) * HW + y * W + x0;
    const int n = CC * 64;
    for (int idx = tid; idx < n; idx += 256) {
        const int cc = idx >> 6, i = idx & 63;
        lds[i * 129 + cc] = fbase[(size_t)cc * HW + i];
    }
    __syncthreads();
    const int wave = tid >> 6, lane = tid & 63;
    const u32* sp = slot_of_src + (size_t)b * HW + y * W + x0;
    for (int p = wave * 16; p < wave * 16 + 16; ++p) {
        const u32 s = sp[p];
        if (s == 0xFFFFFFFFu) continue;
        float* dst = packed + (size_t)s * CC;
        for (int j = lane; j < CC; j += 64)
            dst[j] = lds[p * 129 + j];
    }
}

// ---------------- 8-pixel-wave gather: depth-2 cross-cell + inner-run pipeline ----------------
// Cell boundaries computed as off[i] + bsum[i>>10] (scan_add not run on this path).
// OUT writes non-temporal so the L3-resident packed buffer isn't evicted.

#define KM1(K) ((K) >= 1 ? (K) - 1 : 0)
#define KK(K)  ((K) <= 7 ? (K) : 0)

#define ACCUM(K, w0, w1, dx_, dy_)                                             \
    if ((K) >= 1) {                                                            \
        acc0[KM1(K)] = fmaf(w0, dx_, acc0[KM1(K)]);                            \
        acc1[KM1(K)] = fmaf(w0, dy_, acc1[KM1(K)]);                            \
        den [KM1(K)] += w0;                                                    \
    }                                                                          \
    if ((K) <= 7) {                                                            \
        acc0[KK(K)] = fmaf(w1, dx_, acc0[KK(K)]);                              \
        acc1[KK(K)] = fmaf(w1, dy_, acc1[KK(K)]);                              \
        den [KK(K)] += w1;                                                     \
    }

#define PROC(K, xy, du)                                                        \
    {                                                                          \
        const float fr = (xy).x - (float)(oxw - 1 + (K));                      \
        const float wy = 1.f - fabsf((xy).y - foy);                            \
        const float w0 = (1.f - fr) * wy, w1 = fr * wy;                        \
        const float dx_ = __uint_as_float((du) << 16);                         \
        const float dy_ = __uint_as_float((du) & 0xffff0000u);                 \
        ACCUM(K, w0, w1, dx_, dy_)                                             \
    }

#define RUN(K, bnd, xy_c, du_c)                                                \
    if (bnd[K] < bnd[(K) + 1]) {                                               \
        PROC(K, xy_c, du_c)                                                    \
        u32 i = bnd[K] + 1;                                                    \
        if (i < bnd[(K) + 1]) {                                                \
            float2 xyp = lxy[i];                                               \
            u32    dup = pk[(size_t)i * 64 + lane];                            \
            for (++i; i < bnd[(K) + 1]; ++i) {                                 \
                const float2 xyn = lxy[i];                                     \
                const u32    dun = pk[(size_t)i * 64 + lane];                  \
                PROC(K, xyp, dup)                                              \
                xyp = xyn; dup = dun;                                          \
            }                                                                  \
            PROC(K, xyp, dup)                                                  \
        }                                                                      \
    }

#define BIA(K) bndA[(K) <= 9 ? (K) : 9]
#define BIB(K) bndB[(K) <= 9 ? (K) : 9]

#define STAGE(K)                                                               \
    {                                                                          \
        const u32 nAi = BIA((K) + 2) < SM1 ? BIA((K) + 2) : SM1;               \
        const u32 nBi = BIB((K) + 2) < SM1 ? BIB((K) + 2) : SM1;               \
        const float2 xyA_n = lxy[nAi]; const u32 duA_n = pk[(size_t)nAi * 64 + lane]; \
        const float2 xyB_n = lxy[nBi]; const u32 duB_n = pk[(size_t)nBi * 64 + lane]; \
        RUN(K, bndA, xyA_c, duA_c)                                             \
        RUN(K, bndB, xyB_c, duB_c)                                             \
        xyA_c = xyA_m; duA_c = duA_m; xyA_m = xyA_n; duA_m = duA_n;            \
        xyB_c = xyB_m; duB_c = duB_m; xyB_m = xyB_n; duB_m = duB_n;            \
    }

__global__ __launch_bounds__(256) void gather_cells(
    const u32* __restrict__ pk, const u32* __restrict__ off,
    const u32* __restrict__ bsum, const float2* __restrict__ lxy,
    float* __restrict__ out)
{
    __shared__ float lds[32 * 65];    // 8.5 KB padded transpose tile
    __shared__ float ldsden[32];
    const int tid = threadIdx.x, wv = tid >> 6, lane = tid & 63;
    // XCD-bijective swizzle: 16384 blocks = 8 XCDs x 2048; each XCD owns one
    // batch (8 xseg x 256 rows), rows fastest -> cell-row reuse in that XCD's L2.
    const u32 bid = blockIdx.x;
    const u32 swz = (bid & 7u) * 2048u + (bid >> 3);
    const int b    = (int)(swz >> 11);
    const int xseg = (int)((swz >> 8) & 7u);
    const int row  = (int)(swz & 255u);
    const int ox0  = xseg * 32;            // block's first output x (32 px/block)
    const int oxw  = ox0 + wv * 8;         // this wave's first output x (8 px/wave)
    const float foy = (float)row;

    float acc0[8], acc1[8], den[8];
    #pragma unroll
    for (int k = 0; k < 8; ++k) { acc0[k] = 0.f; acc1[k] = 0.f; den[k] = 0.f; }

    // wave-uniform boundary base -> scalar loads; final = off[i] + bsum[i>>10]
    const u32 rbu = (u32)__builtin_amdgcn_readfirstlane(
        (int)((u32)((b * PH + row) * PW + oxw)));
    u32 bndA[10], bndB[10];
    #pragma unroll
    for (int q = 0; q < 10; ++q) {
        const u32 ia = rbu + q, ib = rbu + PW + q;
        bndA[q] = off[ia] + bsum[ia >> 10];   // cell-row above (padded row = row)
        bndB[q] = off[ib] + bsum[ib >> 10];   // cell-row at    (padded row = row+1)
    }

    // pipeline prologue: first entries of cells 0 (cur) and 1 (mid)
    float2 xyA_c, xyA_m, xyB_c, xyB_m;
    u32 duA_c, duA_m, duB_c, duB_m;
    {
        const u32 a0 = bndA[0] < SM1 ? bndA[0] : SM1;
        const u32 b0 = bndB[0] < SM1 ? bndB[0] : SM1;
        const u32 a1 = bndA[1] < SM1 ? bndA[1] : SM1;
        const u32 b1 = bndB[1] < SM1 ? bndB[1] : SM1;
        xyA_c = lxy[a0]; duA_c = pk[(size_t)a0 * 64 + lane];
        xyB_c = lxy[b0]; duB_c = pk[(size_t)b0 * 64 + lane];
        xyA_m = lxy[a1]; duA_m = pk[(size_t)a1 * 64 + lane];
        xyB_m = lxy[b1]; duB_m = pk[(size_t)b1 * 64 + lane];
    }

    STAGE(0) STAGE(1) STAGE(2) STAGE(3) STAGE(4)
    STAGE(5) STAGE(6) STAGE(7) STAGE(8)

    // ---- epilogue round A: channels 0..63 (acc0, c == lane) ----
    #pragma unroll
    for (int k = 0; k < 8; ++k) {
        const int p = wv * 8 + k;
        lds[p * 65 + lane] = acc0[k];
        if (lane == 0) ldsden[p] = den[k];
    }
    __syncthreads();
    {
        const int px = tid & 31, cslot = tid >> 5;
        const float dn = ldsden[px];
        const float s  = E1 / (E1 * dn + EPS);
        #pragma unroll
        for (int j = 0; j < 8; ++j) {
            const int c = cslot * 8 + j;
            __builtin_nontemporal_store(
                lds[px * 65 + c] * s,
                &out[(size_t)(b * C + c) * HW + (size_t)row * W + ox0 + px]);
        }
    }
    __syncthreads();
    // ---- epilogue round B: channels 64..127 (acc1) ----
    #pragma unroll
    for (int k = 0; k < 8; ++k) {
        const int p = wv * 8 + k;
        lds[p * 65 + lane] = acc1[k];
    }
    __syncthreads();
    {
        const int px = tid & 31, cslot = tid >> 5;
        const float dn = ldsden[px];
        const float s  = E1 / (E1 * dn + EPS);
        #pragma unroll
        for (int j = 0; j < 8; ++j) {
            const int c = cslot * 8 + j;
            __builtin_nontemporal_store(
                lds[px * 65 + c] * s,
                &out[(size_t)(b * C + 64 + c) * HW + (size_t)row * W + ox0 + px]);
        }
    }
    if (tid < 32)
        __builtin_nontemporal_store(
            1.0f,
            &out[(size_t)(B * C) * HW + (size_t)b * HW + (size_t)row * W + ox0 + tid]);
}

// ---------------- fallback: per-thread gather from f32 packed (CC<128) ----------------

__global__ __launch_bounds__(256) void gather_packed(
    const float* __restrict__ packed, const u32* __restrict__ off,
    const float2* __restrict__ lxy, float* __restrict__ out, int c0, int CC)
{
    const int t = threadIdx.x;
    const int tile = blockIdx.x, b = blockIdx.y;
    const int ox = ((tile & 15) << 4) | (t & 15);
    const int oy = ((tile >> 4) << 4) | (t >> 4);
    const int opix = oy * W + ox;
    const u32 rb0 = (u32)((b * PH + oy) * PW + ox);
    const u32 s0 = off[rb0],      e0 = off[rb0 + 2];
    const u32 s1 = off[rb0 + PW], e1 = off[rb0 + PW + 2];
    const float fox = (float)ox, foy = (float)oy;
    float scale = 0.f;
    for (int ch = 0; ch < CC; ch += 16) {
        float acc[16];
        #pragma unroll
        for (int c = 0; c < 16; ++c) acc[c] = 0.f;
        float den = 0.f;
        for (int rr = 0; rr < 2; ++rr) {
            u32 i = rr ? s1 : s0;
            const u32 e = rr ? e1 : e0;
            for (; i < e; ++i) {
                const float2 xy = lxy[i];
                const float w = (1.f - fabsf(xy.x - fox)) * (1.f - fabsf(xy.y - foy));
                den += w;
                const float4* ep = (const float4*)(packed + (size_t)i * CC + ch);
                const float4 q0 = ep[0], q1 = ep[1], q2 = ep[2], q3 = ep[3];
                acc[ 0] = fmaf(w, q0.x, acc[ 0]); acc[ 1] = fmaf(w, q0.y, acc[ 1]);
                acc[ 2] = fmaf(w, q0.z, acc[ 2]); acc[ 3] = fmaf(w, q0.w, acc[ 3]);
                acc[ 4] = fmaf(w, q1.x, acc[ 4]); acc[ 5] = fmaf(w, q1.y, acc[ 5]);
                acc[ 6] = fmaf(w, q1.z, acc[ 6]); acc[ 7] = fmaf(w, q1.w, acc[ 7]);
                acc[ 8] = fmaf(w, q2.x, acc[ 8]); acc[ 9] = fmaf(w, q2.y, acc[ 9]);
                acc[10] = fmaf(w, q2.z, acc[10]); acc[11] = fmaf(w, q2.w, acc[11]);
                acc[12] = fmaf(w, q3.x, acc[12]); acc[13] = fmaf(w, q3.y, acc[13]);
                acc[14] = fmaf(w, q3.z, acc[14]); acc[15] = fmaf(w, q3.w, acc[15]);
            }
        }
        if (ch == 0) scale = E1 / (E1 * den + EPS);
        float* op = out + (size_t)(b * C + c0 + ch) * HW + opix;
        #pragma unroll
        for (int c = 0; c < 16; ++c) op[(size_t)c * HW] = acc[c] * scale;
    }
    if (c0 == 0)
        out[(size_t)(B * C) * HW + (size_t)b * HW + opix] = 1.0f;
}

// ---------------- fallback: planar gather ----------------

__global__ __launch_bounds__(256) void gather_kernel(
    const float* __restrict__ feat, const u32* __restrict__ off,
    const u32* __restrict__ lpos, const float2* __restrict__ lxy,
    float* __restrict__ out)
{
    const int t = threadIdx.x;
    const int tile = blockIdx.x, b = blockIdx.y;
    const int ox = ((tile & 15) << 4) | (t & 15);
    const int oy = ((tile >> 4) << 4) | (t >> 4);
    const int opix = oy * W + ox;
    const u32 rb0 = (u32)((b * PH + oy) * PW + ox);
    const u32 s0 = off[rb0],      e0 = off[rb0 + 2];
    const u32 s1 = off[rb0 + PW], e1 = off[rb0 + PW + 2];
    const float fox = (float)ox, foy = (float)oy;
    float den = 0.f;
    for (int rr = 0; rr < 2; ++rr) {
        u32 i = rr ? s1 : s0;
        const u32 e = rr ? e1 : e0;
        for (; i < e; ++i) {
            const float2 xy = lxy[i];
            den += (1.f - fabsf(xy.x - fox)) * (1.f - fabsf(xy.y - foy));
        }
    }
    const float scale = E1 / (E1 * den + EPS);
    for (int ch = 0; ch < C; ch += 16) {
        float acc[16];
        #pragma unroll
        for (int c = 0; c < 16; ++c) acc[c] = 0.f;
        const float* fb = feat + (size_t)(b * C + ch) * HW;
        for (int rr = 0; rr < 2; ++rr) {
            u32 i = rr ? s1 : s0;
            const u32 e = rr ? e1 : e0;
            for (; i < e; ++i) {
                const float2 xy = lxy[i];
                const float w = (1.f - fabsf(xy.x - fox)) * (1.f - fabsf(xy.y - foy));
                const float* fp = fb + lpos[i];
                #pragma unroll
                for (int c = 0; c < 16; ++c)
                    acc[c] = fmaf(w, fp[(size_t)c * HW], acc[c]);
            }
        }
        float* op = out + (size_t)(b * C + ch) * HW + opix;
        #pragma unroll
        for (int c = 0; c < 16; ++c) op[(size_t)c * HW] = acc[c] * scale;
    }
    out[(size_t)(B * C) * HW + (size_t)b * HW + opix] = 1.0f;
}

// ---------------- fallback: round-1 atomic path ----------------

static constexpr int CG = 8, CPG = C / CG;

__global__ __launch_bounds__(256) void splat_kernel(
    const float* __restrict__ feat, const float* __restrict__ flow,
    float* __restrict__ num, float* __restrict__ den)
{
    const int x = threadIdx.x, by = blockIdx.x, b = by >> 8, y = by & (H - 1);
    const int cg = blockIdx.y;
    const float fx = (float)x + flow[(b * 2 * H + y) * W + x];
    const float fy = (float)y + flow[((b * 2 + 1) * H + y) * W + x];
    const float x0f = floorf(fx), y0f = floorf(fy);
    const int ix0 = (int)x0f, iy0 = (int)y0f;
    const float ax = fx - x0f, ay = fy - y0f;
    const float w00 = (1.f - ax) * (1.f - ay), w10 = ax * (1.f - ay);
    const float w01 = (1.f - ax) * ay,         w11 = ax * ay;
    const bool vx0 = (unsigned)ix0       < (unsigned)W;
    const bool vx1 = (unsigned)(ix0 + 1) < (unsigned)W;
    const bool vy0 = (unsigned)iy0       < (unsigned)H;
    const bool vy1 = (unsigned)(iy0 + 1) < (unsigned)H;
    const bool v00 = vx0 && vy0, v10 = vx1 && vy0;
    const bool v01 = vx0 && vy1, v11 = vx1 && vy1;
    const int t00 = iy0 * W + ix0, t01 = t00 + W;
    if (cg == 0) {
        float* dn = den + b * HW;
        if (v00) atomicAdd(dn + t00,     w00);
        if (v10) atomicAdd(dn + t00 + 1, w10);
        if (v01) atomicAdd(dn + t01,     w01);
        if (v11) atomicAdd(dn + t01 + 1, w11);
    }
    const int c0 = cg * CPG;
    const float* fp = feat + ((size_t)(b * C + c0)) * HW + y * W + x;
    float*       np = num  + ((size_t)(b * C + c0)) * HW;
    for (int c = 0; c < CPG; ++c) {
        const float v = fp[(size_t)c * HW];
        float* nc = np + (size_t)c * HW;
        if (v00) atomicAdd(nc + t00,     v * w00);
        if (v10) atomicAdd(nc + t00 + 1, v * w10);
        if (v01) atomicAdd(nc + t01,     v * w01);
        if (v11) atomicAdd(nc + t01 + 1, v * w11);
    }
}

__global__ __launch_bounds__(256) void normalize_kernel(float* __restrict__ num,
                                                        float* __restrict__ den)
{
    const int x = threadIdx.x, by = blockIdx.x, b = by >> 8;
    const int pix = by * W + x;
    const float d = den[pix];
    const float s = E1 / (E1 * d + EPS);
    float* p = num + (size_t)b * (C - 1) * HW + pix;
    for (int c = 0; c < C; ++c) p[(size_t)c * HW] *= s;
    den[pix] = 1.0f;
}

// ---------------- launch ----------------

extern "C" void kernel_launch(void* const* d_in, const int* in_sizes, int n_in,
                              void* d_out, int out_size, void* d_ws, size_t ws_size,
                              hipStream_t stream) {
    const float* feat = (const float*)d_in[0];
    const float* flow = (const float*)d_in[1];
    float* out = (float*)d_out;

    const size_t o_counts = 0;
    const size_t o_off    = o_counts + (size_t)NC * 4;
    const size_t o_bsum   = (o_off + (size_t)(NC + 1) * 4 + 15) & ~(size_t)15;
    const size_t o_slot   = (o_bsum + 4096 + 15) & ~(size_t)15;
    const size_t o_lpos   = o_slot + (size_t)S * 4;
    const size_t o_lxy    = (o_lpos + (size_t)S * 4 + 15) & ~(size_t)15;
    const size_t meta_end = o_lxy + (size_t)S * 8;               // ~16.5 MB
    const size_t o_packed = (meta_end + 255) & ~(size_t)255;

    // bf16 main path needs S*64*4 = 128 MB of packed; f32 fallbacks tiered below
    const bool bf16_ok = (o_packed + (size_t)S * 64 * 4) <= ws_size;
    int CC = 0;
    if (!bf16_ok)
        for (int cand = 64; cand >= 16; cand >>= 1)
            if (o_packed + (size_t)S * cand * 4 <= ws_size) { CC = cand; break; }

    if (meta_end <= ws_size) {
        u32*    counts = (u32*)   ((char*)d_ws + o_counts);
        u32*    off    = (u32*)   ((char*)d_ws + o_off);
        u32*    bsum   = (u32*)   ((char*)d_ws + o_bsum);
        u32*    slot   = (u32*)   ((char*)d_ws + o_slot);
        u32*    lpos   = (u32*)   ((char*)d_ws + o_lpos);
        float2* lxy    = (float2*)((char*)d_ws + o_lxy);
        void*   packed = (void*)  ((char*)d_ws + o_packed);

        hipMemsetAsync(counts, 0, (size_t)NC * 4, stream);
        count_kernel<<<B * H, 256, 0, stream>>>(flow, counts);
        scan_blocks<<<NBLK, 256, 0, stream>>>(counts, off, bsum);
        scan_bsum<<<1, 1024, 0, stream>>>(bsum, off);

        if (bf16_ok) {
            // fused: slot claim + lxy + bf16 pack (consumes counts down to 0)
            pack128_fused<<<dim3(W / 64, H, B), 256, 0, stream>>>(
                feat, flow, off, bsum, counts, (u32*)packed, lxy);
            gather_cells<<<B * H * (W / 32), 256, 0, stream>>>(
                (const u32*)packed, off, bsum, lxy, out);
        } else if (CC) {
            scan_add<<<NBLK, 256, 0, stream>>>(off, bsum);
            fill_kernel<<<B * H, 256, 0, stream>>>(flow, off, counts, slot, lpos, lxy);
            for (int c0 = 0; c0 < C; c0 += CC) {
                pack_kernel<<<dim3(W / 64, H, B), 256, 0, stream>>>(
                    feat, slot, (float*)packed, c0, CC);
                gather_packed<<<dim3(256, B), 256, 0, stream>>>(
                    (const float*)packed, off, lxy, out, c0, CC);
            }
        } else {
            scan_add<<<NBLK, 256, 0, stream>>>(off, bsum);
            fill_kernel<<<B * H, 256, 0, stream>>>(flow, off, counts, slot, lpos, lxy);
            gather_kernel<<<dim3(256, B), 256, 0, stream>>>(feat, off, lpos, lxy, out);
        }
    } else {
        float* num = out;
        float* den = out + (size_t)B * C * HW;
        hipMemsetAsync(d_out, 0, (size_t)out_size * sizeof(float), stream);
        splat_kernel<<<dim3(B * H, CG), 256, 0, stream>>>(feat, flow, num, den);
        normalize_kernel<<<B * H, 256, 0, stream>>>(num, den);
    }
}

// Round 14
// 186.448 us; speedup vs baseline: 1.6501x; 1.0033x over previous
//
#include <hip/hip_runtime.h>

// Softmax splatting (softsplat 'soft', metric==1) via destination-binned GATHER.
// Round 14: depth-3 cross-cell prefetch in the gather walk (was depth-2).
// Retains r13: fused pack (slot claim + bf16 pack), scan_add dropped in main
// path, NT feat loads, NT out stores, L3-resident 128 MB bf16 packed buffer.
// B=8, C=128, H=256, W=256, f32. out = [warped (B,C,H,W) | metric (B,1,H,W)=1]

typedef unsigned int u32;
typedef float f32x4 __attribute__((ext_vector_type(4)));

static constexpr int B = 8, C = 128, H = 256, W = 256;
static constexpr int HW = H * W;
static constexpr int PH = H + 1, PW = W + 1;         // padded floor-cell grid
static constexpr int NC = B * PH * PW;               // 528392 cells
static constexpr int S  = B * HW;                    // 524288 sources
static constexpr u32 SM1 = (u32)(S - 1);
static constexpr float E1  = 2.7182818284590452354f; // exp(1) (metric == 1)
static constexpr float EPS = 1e-7f;
static constexpr int CHUNK = 1024;
static constexpr int NBLK  = (NC + CHUNK - 1) / CHUNK;  // 517
static constexpr int LASTCH = NC / CHUNK;            // chunk containing index NC (516)

__device__ __forceinline__ u32 bf16rne(float f) {
    const u32 u = __float_as_uint(f);
    return (u + 0x7fffu + ((u >> 16) & 1u)) >> 16;
}

// ---------------- binning ----------------

__global__ __launch_bounds__(256) void count_kernel(const float* __restrict__ flow,
                                                    u32* __restrict__ counts)
{
    const int x = threadIdx.x, by = blockIdx.x, b = by >> 8, y = by & 255;
    const float fx = (float)x + flow[(b * 2) * HW + y * W + x];
    const float fy = (float)y + flow[(b * 2 + 1) * HW + y * W + x];
    const int ix0 = (int)floorf(fx), iy0 = (int)floorf(fy);
    if (ix0 >= -1 && ix0 < W && iy0 >= -1 && iy0 < H)
        atomicAdd(&counts[(b * PH + iy0 + 1) * PW + (ix0 + 1)], 1u);
}

__global__ __launch_bounds__(256) void scan_blocks(const u32* __restrict__ in,
                                                   u32* __restrict__ out,
                                                   u32* __restrict__ bsum)
{
    __shared__ u32 sd[256];
    const int tid = threadIdx.x;
    const int base = blockIdx.x * CHUNK + tid * 4;
    u32 v0 = 0, v1 = 0, v2 = 0, v3 = 0;
    if (base + 3 < NC) {
        const uint4 q = *(const uint4*)(in + base);
        v0 = q.x; v1 = q.y; v2 = q.z; v3 = q.w;
    } else {
        if (base     < NC) v0 = in[base];
        if (base + 1 < NC) v1 = in[base + 1];
        if (base + 2 < NC) v2 = in[base + 2];
    }
    const u32 t = v0 + v1 + v2 + v3;
    sd[tid] = t; __syncthreads();
    for (int o = 1; o < 256; o <<= 1) {
        const u32 a = (tid >= o) ? sd[tid - o] : 0u;
        __syncthreads();
        sd[tid] += a;
        __syncthreads();
    }
    const u32 excl = sd[tid] - t;
    if (base + 3 < NC) {
        uint4 q; q.x = excl; q.y = excl + v0; q.z = excl + v0 + v1; q.w = excl + v0 + v1 + v2;
        *(uint4*)(out + base) = q;
    } else {
        if (base     < NC) out[base]     = excl;
        if (base + 1 < NC) out[base + 1] = excl + v0;
        if (base + 2 < NC) out[base + 2] = excl + v0 + v1;
    }
    if (tid == 255) bsum[blockIdx.x] = sd[255];
}

// bsum -> exclusive scan; off[NC] set so that off[NC] + bsum[LASTCH] == total
__global__ __launch_bounds__(1024) void scan_bsum(u32* __restrict__ bsum,
                                                  u32* __restrict__ off)
{
    __shared__ u32 sd[1024];
    const int tid = threadIdx.x;
    const u32 v = (tid < NBLK) ? bsum[tid] : 0u;
    sd[tid] = v; __syncthreads();
    for (int o = 1; o < 1024; o <<= 1) {
        const u32 a = (tid >= o) ? sd[tid - o] : 0u;
        __syncthreads();
        sd[tid] += a;
        __syncthreads();
    }
    if (tid < NBLK) bsum[tid] = sd[tid] - v;
    if (tid == LASTCH) off[NC] = sd[1023] - (sd[tid] - v);
}

// fallback-path only: bake bsum into off (and fix off[NC] to plain total)
__global__ __launch_bounds__(256) void scan_add(u32* __restrict__ off,
                                                const u32* __restrict__ bsum)
{
    const u32 add = bsum[blockIdx.x];
    if (blockIdx.x == NBLK - 1 && threadIdx.x == 255) off[NC] += bsum[LASTCH];
    if (add == 0) return;
    const int base = blockIdx.x * CHUNK + threadIdx.x * 4;
    if (base + 3 < NC) {
        uint4 q = *(uint4*)(off + base);
        q.x += add; q.y += add; q.z += add; q.w += add;
        *(uint4*)(off + base) = q;
    } else {
        for (int k = 0; k < 4; ++k)
            if (base + k < NC) off[base + k] += add;
    }
}

// fallback-path fill (after scan_add; claims slots by decrementing counts)
__global__ __launch_bounds__(256) void fill_kernel(const float* __restrict__ flow,
                                                   const u32* __restrict__ off,
                                                   u32* __restrict__ cnt,
                                                   u32* __restrict__ slot_of_src,
                                                   u32* __restrict__ lpos,
                                                   float2* __restrict__ lxy)
{
    const int x = threadIdx.x, by = blockIdx.x, b = by >> 8, y = by & 255;
    const float fx = (float)x + flow[(b * 2) * HW + y * W + x];
    const float fy = (float)y + flow[(b * 2 + 1) * HW + y * W + x];
    const int ix0 = (int)floorf(fx), iy0 = (int)floorf(fy);
    const int src = b * HW + y * W + x;
    if (ix0 >= -1 && ix0 < W && iy0 >= -1 && iy0 < H) {
        const int cell = (b * PH + iy0 + 1) * PW + (ix0 + 1);
        const u32 old = atomicSub(&cnt[cell], 1u);
        const u32 slot = off[cell] + old - 1u;
        slot_of_src[src] = slot;
        lpos[slot] = (u32)(y * W + x);
        lxy[slot]  = make_float2(fx, fy);
    } else {
        slot_of_src[src] = 0xFFFFFFFFu;
    }
}

// ---------------- fused pack (bf16): slot claim + lxy write + pack ----------------

__global__ __launch_bounds__(256) void pack128_fused(const float* __restrict__ feat,
                                                     const float* __restrict__ flow,
                                                     const u32* __restrict__ off,
                                                     const u32* __restrict__ bsum,
                                                     u32* __restrict__ cnt,
                                                     u32* __restrict__ packed,
                                                     float2* __restrict__ lxy)
{
    __shared__ unsigned short lds[64 * 129];   // 16.5 KB: [pix][ch] bf16
    __shared__ u32 sslot[64];
    const int x0 = blockIdx.x * 64, y = blockIdx.y, b = blockIdx.z;
    const int tid = threadIdx.x;

    if (tid < 64) {   // slot claim for this block's 64 source pixels
        const int x = x0 + tid;
        const float fx = (float)x + flow[(b * 2) * HW + y * W + x];
        const float fy = (float)y + flow[(b * 2 + 1) * HW + y * W + x];
        const int ix0 = (int)floorf(fx), iy0 = (int)floorf(fy);
        if (ix0 >= -1 && ix0 < W && iy0 >= -1 && iy0 < H) {
            const int cell = (b * PH + iy0 + 1) * PW + (ix0 + 1);
            const u32 old = atomicSub(&cnt[cell], 1u);
            const u32 slot = off[cell] + bsum[cell >> 10] + old - 1u;
            sslot[tid] = slot;
            lxy[slot]  = make_float2(fx, fy);
        } else {
            sslot[tid] = 0xFFFFFFFFu;
        }
    }

    const float* fbase = feat + (size_t)(b * C) * HW + y * W + x0;
    for (int idx = tid; idx < 128 * 16; idx += 256) {
        const int cc = idx >> 4, i4 = (idx & 15) * 4;
        const f32x4 v = __builtin_nontemporal_load(
            (const f32x4*)(fbase + (size_t)cc * HW + i4));
        lds[(i4 + 0) * 129 + cc] = (unsigned short)bf16rne(v.x);
        lds[(i4 + 1) * 129 + cc] = (unsigned short)bf16rne(v.y);
        lds[(i4 + 2) * 129 + cc] = (unsigned short)bf16rne(v.z);
        lds[(i4 + 3) * 129 + cc] = (unsigned short)bf16rne(v.w);
    }
    __syncthreads();

    const int wave = tid >> 6, lane = tid & 63;
    for (int p = wave * 16; p < wave * 16 + 16; ++p) {
        const u32 s = sslot[p];
        if (s == 0xFFFFFFFFu) continue;
        const u32 lo = (u32)lds[p * 129 + lane];
        const u32 hi = (u32)lds[p * 129 + 64 + lane];
        packed[(size_t)s * 64 + lane] = lo | (hi << 16);
    }
}

// generic f32 pack (fallback path, CC<128, linear layout; needs fill's slot map)
__global__ __launch_bounds__(256) void pack_kernel(const float* __restrict__ feat,
                                                   const u32* __restrict__ slot_of_src,
                                                   float* __restrict__ packed,
                                                   int c0, int CC)
{
    __shared__ float lds[64 * 129];
    const int x0 = blockIdx.x * 64, y = blockIdx.y, b = blockIdx.z;
    const int tid = threadIdx.x;
    const float* fbase = feat + (size_t)(b * C + c0) * HW + y * W + x0;
    const int n = CC * 64;
    for (int idx = tid; idx < n; idx += 256) {
        const int cc = idx >> 6, i = idx & 63;
        lds[i * 129 + cc] = fbase[(size_t)cc * HW + i];
    }
    __syncthreads();
    const int wave = tid >> 6, lane = tid & 63;
    const u32* sp = slot_of_src + (size_t)b * HW + y * W + x0;
    for (int p = wave * 16; p < wave * 16 + 16; ++p) {
        const u32 s = sp[p];
        if (s == 0xFFFFFFFFu) continue;
        float* dst = packed + (size_t)s * CC;
        for (int j = lane; j < CC; j += 64)
            dst[j] = lds[p * 129 + j];
    }
}

// ---------------- 8-pixel-wave gather: depth-3 cross-cell + inner-run pipeline ----------------

#define KM1(K) ((K) >= 1 ? (K) - 1 : 0)
#define KK(K)  ((K) <= 7 ? (K) : 0)

#define ACCUM(K, w0, w1, dx_, dy_)                                             \
    if ((K) >= 1) {                                                            \
        acc0[KM1(K)] = fmaf(w0, dx_, acc0[KM1(K)]);                            \
        acc1[KM1(K)] = fmaf(w0, dy_, acc1[KM1(K)]);                            \
        den [KM1(K)] += w0;                                                    \
    }                                                                          \
    if ((K) <= 7) {                                                            \
        acc0[KK(K)] = fmaf(w1, dx_, acc0[KK(K)]);                              \
        acc1[KK(K)] = fmaf(w1, dy_, acc1[KK(K)]);                              \
        den [KK(K)] += w1;                                                     \
    }

#define PROC(K, xy, du)                                                        \
    {                                                                          \
        const float fr = (xy).x - (float)(oxw - 1 + (K));                      \
        const float wy = 1.f - fabsf((xy).y - foy);                            \
        const float w0 = (1.f - fr) * wy, w1 = fr * wy;                        \
        const float dx_ = __uint_as_float((du) << 16);                         \
        const float dy_ = __uint_as_float((du) & 0xffff0000u);                 \
        ACCUM(K, w0, w1, dx_, dy_)                                             \
    }

#define RUN(K, bnd, xy_c, du_c)                                                \
    if (bnd[K] < bnd[(K) + 1]) {                                               \
        PROC(K, xy_c, du_c)                                                    \
        u32 i = bnd[K] + 1;                                                    \
        if (i < bnd[(K) + 1]) {                                                \
            float2 xyp = lxy[i];                                               \
            u32    dup = pk[(size_t)i * 64 + lane];                            \
            for (++i; i < bnd[(K) + 1]; ++i) {                                 \
                const float2 xyn = lxy[i];                                     \
                const u32    dun = pk[(size_t)i * 64 + lane];                  \
                PROC(K, xyp, dup)                                              \
                xyp = xyn; dup = dun;                                          \
            }                                                                  \
            PROC(K, xyp, dup)                                                  \
        }                                                                      \
    }

#define BIA(K) bndA[(K) <= 9 ? (K) : 9]
#define BIB(K) bndB[(K) <= 9 ? (K) : 9]

#define STAGE(K)                                                               \
    {                                                                          \
        const u32 nAi = BIA((K) + 3) < SM1 ? BIA((K) + 3) : SM1;               \
        const u32 nBi = BIB((K) + 3) < SM1 ? BIB((K) + 3) : SM1;               \
        const float2 xyA_n = lxy[nAi]; const u32 duA_n = pk[(size_t)nAi * 64 + lane]; \
        const float2 xyB_n = lxy[nBi]; const u32 duB_n = pk[(size_t)nBi * 64 + lane]; \
        RUN(K, bndA, xyA_c, duA_c)                                             \
        RUN(K, bndB, xyB_c, duB_c)                                             \
        xyA_c = xyA_m; duA_c = duA_m; xyA_m = xyA_2; duA_m = duA_2;            \
        xyA_2 = xyA_n; duA_2 = duA_n;                                          \
        xyB_c = xyB_m; duB_c = duB_m; xyB_m = xyB_2; duB_m = duB_2;            \
        xyB_2 = xyB_n; duB_2 = duB_n;                                          \
    }

__global__ __launch_bounds__(256) void gather_cells(
    const u32* __restrict__ pk, const u32* __restrict__ off,
    const u32* __restrict__ bsum, const float2* __restrict__ lxy,
    float* __restrict__ out)
{
    __shared__ float lds[32 * 65];    // 8.5 KB padded transpose tile
    __shared__ float ldsden[32];
    const int tid = threadIdx.x, wv = tid >> 6, lane = tid & 63;
    // XCD-bijective swizzle: 16384 blocks = 8 XCDs x 2048; each XCD owns one
    // batch (8 xseg x 256 rows), rows fastest -> cell-row reuse in that XCD's L2.
    const u32 bid = blockIdx.x;
    const u32 swz = (bid & 7u) * 2048u + (bid >> 3);
    const int b    = (int)(swz >> 11);
    const int xseg = (int)((swz >> 8) & 7u);
    const int row  = (int)(swz & 255u);
    const int ox0  = xseg * 32;            // block's first output x (32 px/block)
    const int oxw  = ox0 + wv * 8;         // this wave's first output x (8 px/wave)
    const float foy = (float)row;

    float acc0[8], acc1[8], den[8];
    #pragma unroll
    for (int k = 0; k < 8; ++k) { acc0[k] = 0.f; acc1[k] = 0.f; den[k] = 0.f; }

    // wave-uniform boundary base -> scalar loads; final = off[i] + bsum[i>>10]
    const u32 rbu = (u32)__builtin_amdgcn_readfirstlane(
        (int)((u32)((b * PH + row) * PW + oxw)));
    u32 bndA[10], bndB[10];
    #pragma unroll
    for (int q = 0; q < 10; ++q) {
        const u32 ia = rbu + q, ib = rbu + PW + q;
        bndA[q] = off[ia] + bsum[ia >> 10];   // cell-row above (padded row = row)
        bndB[q] = off[ib] + bsum[ib >> 10];   // cell-row at    (padded row = row+1)
    }

    // pipeline prologue: first entries of cells 0 (cur), 1 (mid), 2 (mid2)
    float2 xyA_c, xyA_m, xyA_2, xyB_c, xyB_m, xyB_2;
    u32 duA_c, duA_m, duA_2, duB_c, duB_m, duB_2;
    {
        const u32 a0 = bndA[0] < SM1 ? bndA[0] : SM1;
        const u32 b0 = bndB[0] < SM1 ? bndB[0] : SM1;
        const u32 a1 = bndA[1] < SM1 ? bndA[1] : SM1;
        const u32 b1 = bndB[1] < SM1 ? bndB[1] : SM1;
        const u32 a2 = bndA[2] < SM1 ? bndA[2] : SM1;
        const u32 b2 = bndB[2] < SM1 ? bndB[2] : SM1;
        xyA_c = lxy[a0]; duA_c = pk[(size_t)a0 * 64 + lane];
        xyB_c = lxy[b0]; duB_c = pk[(size_t)b0 * 64 + lane];
        xyA_m = lxy[a1]; duA_m = pk[(size_t)a1 * 64 + lane];
        xyB_m = lxy[b1]; duB_m = pk[(size_t)b1 * 64 + lane];
        xyA_2 = lxy[a2]; duA_2 = pk[(size_t)a2 * 64 + lane];
        xyB_2 = lxy[b2]; duB_2 = pk[(size_t)b2 * 64 + lane];
    }

    STAGE(0) STAGE(1) STAGE(2) STAGE(3) STAGE(4)
    STAGE(5) STAGE(6) STAGE(7) STAGE(8)

    // ---- epilogue round A: channels 0..63 (acc0, c == lane) ----
    #pragma unroll
    for (int k = 0; k < 8; ++k) {
        const int p = wv * 8 + k;
        lds[p * 65 + lane] = acc0[k];
        if (lane == 0) ldsden[p] = den[k];
    }
    __syncthreads();
    {
        const int px = tid & 31, cslot = tid >> 5;
        const float dn = ldsden[px];
        const float s  = E1 / (E1 * dn + EPS);
        #pragma unroll
        for (int j = 0; j < 8; ++j) {
            const int c = cslot * 8 + j;
            __builtin_nontemporal_store(
                lds[px * 65 + c] * s,
                &out[(size_t)(b * C + c) * HW + (size_t)row * W + ox0 + px]);
        }
    }
    __syncthreads();
    // ---- epilogue round B: channels 64..127 (acc1) ----
    #pragma unroll
    for (int k = 0; k < 8; ++k) {
        const int p = wv * 8 + k;
        lds[p * 65 + lane] = acc1[k];
    }
    __syncthreads();
    {
        const int px = tid & 31, cslot = tid >> 5;
        const float dn = ldsden[px];
        const float s  = E1 / (E1 * dn + EPS);
        #pragma unroll
        for (int j = 0; j < 8; ++j) {
            const int c = cslot * 8 + j;
            __builtin_nontemporal_store(
                lds[px * 65 + c] * s,
                &out[(size_t)(b * C + 64 + c) * HW + (size_t)row * W + ox0 + px]);
        }
    }
    if (tid < 32)
        __builtin_nontemporal_store(
            1.0f,
            &out[(size_t)(B * C) * HW + (size_t)b * HW + (size_t)row * W + ox0 + tid]);
}

// ---------------- fallback: per-thread gather from f32 packed (CC<128) ----------------

__global__ __launch_bounds__(256) void gather_packed(
    const float* __restrict__ packed, const u32* __restrict__ off,
    const float2* __restrict__ lxy, float* __restrict__ out, int c0, int CC)
{
    const int t = threadIdx.x;
    const int tile = blockIdx.x, b = blockIdx.y;
    const int ox = ((tile & 15) << 4) | (t & 15);
    const int oy = ((tile >> 4) << 4) | (t >> 4);
    const int opix = oy * W + ox;
    const u32 rb0 = (u32)((b * PH + oy) * PW + ox);
    const u32 s0 = off[rb0],      e0 = off[rb0 + 2];
    const u32 s1 = off[rb0 + PW], e1 = off[rb0 + PW + 2];
    const float fox = (float)ox, foy = (float)oy;
    float scale = 0.f;
    for (int ch = 0; ch < CC; ch += 16) {
        float acc[16];
        #pragma unroll
        for (int c = 0; c < 16; ++c) acc[c] = 0.f;
        float den = 0.f;
        for (int rr = 0; rr < 2; ++rr) {
            u32 i = rr ? s1 : s0;
            const u32 e = rr ? e1 : e0;
            for (; i < e; ++i) {
                const float2 xy = lxy[i];
                const float w = (1.f - fabsf(xy.x - fox)) * (1.f - fabsf(xy.y - foy));
                den += w;
                const float4* ep = (const float4*)(packed + (size_t)i * CC + ch);
                const float4 q0 = ep[0], q1 = ep[1], q2 = ep[2], q3 = ep[3];
                acc[ 0] = fmaf(w, q0.x, acc[ 0]); acc[ 1] = fmaf(w, q0.y, acc[ 1]);
                acc[ 2] = fmaf(w, q0.z, acc[ 2]); acc[ 3] = fmaf(w, q0.w, acc[ 3]);
                acc[ 4] = fmaf(w, q1.x, acc[ 4]); acc[ 5] = fmaf(w, q1.y, acc[ 5]);
                acc[ 6] = fmaf(w, q1.z, acc[ 6]); acc[ 7] = fmaf(w, q1.w, acc[ 7]);
                acc[ 8] = fmaf(w, q2.x, acc[ 8]); acc[ 9] = fmaf(w, q2.y, acc[ 9]);
                acc[10] = fmaf(w, q2.z, acc[10]); acc[11] = fmaf(w, q2.w, acc[11]);
                acc[12] = fmaf(w, q3.x, acc[12]); acc[13] = fmaf(w, q3.y, acc[13]);
                acc[14] = fmaf(w, q3.z, acc[14]); acc[15] = fmaf(w, q3.w, acc[15]);
            }
        }
        if (ch == 0) scale = E1 / (E1 * den + EPS);
        float* op = out + (size_t)(b * C + c0 + ch) * HW + opix;
        #pragma unroll
        for (int c = 0; c < 16; ++c) op[(size_t)c * HW] = acc[c] * scale;
    }
    if (c0 == 0)
        out[(size_t)(B * C) * HW + (size_t)b * HW + opix] = 1.0f;
}

// ---------------- fallback: planar gather ----------------

__global__ __launch_bounds__(256) void gather_kernel(
    const float* __restrict__ feat, const u32* __restrict__ off,
    const u32* __restrict__ lpos, const float2* __restrict__ lxy,
    float* __restrict__ out)
{
    const int t = threadIdx.x;
    const int tile = blockIdx.x, b = blockIdx.y;
    const int ox = ((tile & 15) << 4) | (t & 15);
    const int oy = ((tile >> 4) << 4) | (t >> 4);
    const int opix = oy * W + ox;
    const u32 rb0 = (u32)((b * PH + oy) * PW + ox);
    const u32 s0 = off[rb0],      e0 = off[rb0 + 2];
    const u32 s1 = off[rb0 + PW], e1 = off[rb0 + PW + 2];
    const float fox = (float)ox, foy = (float)oy;
    float den = 0.f;
    for (int rr = 0; rr < 2; ++rr) {
        u32 i = rr ? s1 : s0;
        const u32 e = rr ? e1 : e0;
        for (; i < e; ++i) {
            const float2 xy = lxy[i];
            den += (1.f - fabsf(xy.x - fox)) * (1.f - fabsf(xy.y - foy));
        }
    }
    const float scale = E1 / (E1 * den + EPS);
    for (int ch = 0; ch < C; ch += 16) {
        float acc[16];
        #pragma unroll
        for (int c = 0; c < 16; ++c) acc[c] = 0.f;
        const float* fb = feat + (size_t)(b * C + ch) * HW;
        for (int rr = 0; rr < 2; ++rr) {
            u32 i = rr ? s1 : s0;
            const u32 e = rr ? e1 : e0;
            for (; i < e; ++i) {
                const float2 xy = lxy[i];
                const float w = (1.f - fabsf(xy.x - fox)) * (1.f - fabsf(xy.y - foy));
                const float* fp = fb + lpos[i];
                #pragma unroll
                for (int c = 0; c < 16; ++c)
                    acc[c] = fmaf(w, fp[(size_t)c * HW], acc[c]);
            }
        }
        float* op = out + (size_t)(b * C + ch) * HW + opix;
        #pragma unroll
        for (int c = 0; c < 16; ++c) op[(size_t)c * HW] = acc[c] * scale;
    }
    out[(size_t)(B * C) * HW + (size_t)b * HW + opix] = 1.0f;
}

// ---------------- fallback: round-1 atomic path ----------------

static constexpr int CG = 8, CPG = C / CG;

__global__ __launch_bounds__(256) void splat_kernel(
    const float* __restrict__ feat, const float* __restrict__ flow,
    float* __restrict__ num, float* __restrict__ den)
{
    const int x = threadIdx.x, by = blockIdx.x, b = by >> 8, y = by & (H - 1);
    const int cg = blockIdx.y;
    const float fx = (float)x + flow[(b * 2 * H + y) * W + x];
    const float fy = (float)y + flow[((b * 2 + 1) * H + y) * W + x];
    const float x0f = floorf(fx), y0f = floorf(fy);
    const int ix0 = (int)x0f, iy0 = (int)y0f;
    const float ax = fx - x0f, ay = fy - y0f;
    const float w00 = (1.f - ax) * (1.f - ay), w10 = ax * (1.f - ay);
    const float w01 = (1.f - ax) * ay,         w11 = ax * ay;
    const bool vx0 = (unsigned)ix0       < (unsigned)W;
    const bool vx1 = (unsigned)(ix0 + 1) < (unsigned)W;
    const bool vy0 = (unsigned)iy0       < (unsigned)H;
    const bool vy1 = (unsigned)(iy0 + 1) < (unsigned)H;
    const bool v00 = vx0 && vy0, v10 = vx1 && vy0;
    const bool v01 = vx0 && vy1, v11 = vx1 && vy1;
    const int t00 = iy0 * W + ix0, t01 = t00 + W;
    if (cg == 0) {
        float* dn = den + b * HW;
        if (v00) atomicAdd(dn + t00,     w00);
        if (v10) atomicAdd(dn + t00 + 1, w10);
        if (v01) atomicAdd(dn + t01,     w01);
        if (v11) atomicAdd(dn + t01 + 1, w11);
    }
    const int c0 = cg * CPG;
    const float* fp = feat + ((size_t)(b * C + c0)) * HW + y * W + x;
    float*       np = num  + ((size_t)(b * C + c0)) * HW;
    for (int c = 0; c < CPG; ++c) {
        const float v = fp[(size_t)c * HW];
        float* nc = np + (size_t)c * HW;
        if (v00) atomicAdd(nc + t00,     v * w00);
        if (v10) atomicAdd(nc + t00 + 1, v * w10);
        if (v01) atomicAdd(nc + t01,     v * w01);
        if (v11) atomicAdd(nc + t01 + 1, v * w11);
    }
}

__global__ __launch_bounds__(256) void normalize_kernel(float* __restrict__ num,
                                                        float* __restrict__ den)
{
    const int x = threadIdx.x, by = blockIdx.x, b = by >> 8;
    const int pix = by * W + x;
    const float d = den[pix];
    const float s = E1 / (E1 * d + EPS);
    float* p = num + (size_t)b * (C - 1) * HW + pix;
    for (int c = 0; c < C; ++c) p[(size_t)c * HW] *= s;
    den[pix] = 1.0f;
}

// ---------------- launch ----------------

extern "C" void kernel_launch(void* const* d_in, const int* in_sizes, int n_in,
                              void* d_out, int out_size, void* d_ws, size_t ws_size,
                              hipStream_t stream) {
    const float* feat = (const float*)d_in[0];
    const float* flow = (const float*)d_in[1];
    float* out = (float*)d_out;

    const size_t o_counts = 0;
    const size_t o_off    = o_counts + (size_t)NC * 4;
    const size_t o_bsum   = (o_off + (size_t)(NC + 1) * 4 + 15) & ~(size_t)15;
    const size_t o_slot   = (o_bsum + 4096 + 15) & ~(size_t)15;
    const size_t o_lpos   = o_slot + (size_t)S * 4;
    const size_t o_lxy    = (o_lpos + (size_t)S * 4 + 15) & ~(size_t)15;
    const size_t meta_end = o_lxy + (size_t)S * 8;               // ~16.5 MB
    const size_t o_packed = (meta_end + 255) & ~(size_t)255;

    // bf16 main path needs S*64*4 = 128 MB of packed; f32 fallbacks tiered below
    const bool bf16_ok = (o_packed + (size_t)S * 64 * 4) <= ws_size;
    int CC = 0;
    if (!bf16_ok)
        for (int cand = 64; cand >= 16; cand >>= 1)
            if (o_packed + (size_t)S * cand * 4 <= ws_size) { CC = cand; break; }

    if (meta_end <= ws_size) {
        u32*    counts = (u32*)   ((char*)d_ws + o_counts);
        u32*    off    = (u32*)   ((char*)d_ws + o_off);
        u32*    bsum   = (u32*)   ((char*)d_ws + o_bsum);
        u32*    slot   = (u32*)   ((char*)d_ws + o_slot);
        u32*    lpos   = (u32*)   ((char*)d_ws + o_lpos);
        float2* lxy    = (float2*)((char*)d_ws + o_lxy);
        void*   packed = (void*)  ((char*)d_ws + o_packed);

        hipMemsetAsync(counts, 0, (size_t)NC * 4, stream);
        count_kernel<<<B * H, 256, 0, stream>>>(flow, counts);
        scan_blocks<<<NBLK, 256, 0, stream>>>(counts, off, bsum);
        scan_bsum<<<1, 1024, 0, stream>>>(bsum, off);

        if (bf16_ok) {
            // fused: slot claim + lxy + bf16 pack (consumes counts down to 0)
            pack128_fused<<<dim3(W / 64, H, B), 256, 0, stream>>>(
                feat, flow, off, bsum, counts, (u32*)packed, lxy);
            gather_cells<<<B * H * (W / 32), 256, 0, stream>>>(
                (const u32*)packed, off, bsum, lxy, out);
        } else if (CC) {
            scan_add<<<NBLK, 256, 0, stream>>>(off, bsum);
            fill_kernel<<<B * H, 256, 0, stream>>>(flow, off, counts, slot, lpos, lxy);
            for (int c0 = 0; c0 < C; c0 += CC) {
                pack_kernel<<<dim3(W / 64, H, B), 256, 0, stream>>>(
                    feat, slot, (float*)packed, c0, CC);
                gather_packed<<<dim3(256, B), 256, 0, stream>>>(
                    (const float*)packed, off, lxy, out, c0, CC);
            }
        } else {
            scan_add<<<NBLK, 256, 0, stream>>>(off, bsum);
            fill_kernel<<<B * H, 256, 0, stream>>>(flow, off, counts, slot, lpos, lxy);
            gather_kernel<<<dim3(256, B), 256, 0, stream>>>(feat, off, lpos, lxy, out);
        }
    } else {
        float* num = out;
        float* den = out + (size_t)B * C * HW;
        hipMemsetAsync(d_out, 0, (size_t)out_size * sizeof(float), stream);
        splat_kernel<<<dim3(B * H, CG), 256, 0, stream>>>(feat, flow, num, den);
        normalize_kernel<<<B * H, 256, 0, stream>>>(num, den);
    }
}